// Round 1
// baseline (2826.700 us; speedup 1.0000x reference)
//
#include <hip/hip_runtime.h>
#include <hip/hip_bf16.h>

// Problem constants (from reference setup_inputs)
// N=2 batch, S=2048 seq, M=1024 d_model, H=16 heads, D=64 head dim
#define NB 2
#define SEQ 2048
#define DMODEL 1024
#define NH 16
#define HD 64

// ---------------------------------------------------------------------------
// GEMM: out = X * W^T + bias
//   X: [R x 1024] row-major (K contiguous)
//   W: [C x 1024] row-major (K contiguous)
//   qkv_mode=1: scatter output to [h][n][s][d] layout (h=c>>6, d=c&63)
//   qkv_mode=0: plain row-major [R x 1024]
// Tile 64x64, 256 threads (16x16), 4x4 acc/thread, K-step 16.
// LDS stored K-major transposed (Xs[k][row]) so compute reads are float4.
// ---------------------------------------------------------------------------
#define TS 64
#define KSTEP 16

__global__ __launch_bounds__(256) void gemm_xwT_f32(
    const float* __restrict__ X, const float* __restrict__ W,
    const float* __restrict__ bias, float* __restrict__ out, int qkv_mode)
{
    const int KD = DMODEL;
    // pad to 68 floats (272B, multiple of 16B) -> float4-aligned, 2-way max alias
    __shared__ float Xs[KSTEP][TS + 4];
    __shared__ float Ws[KSTEP][TS + 4];

    const int tid = threadIdx.x;
    const int tx = tid & 15;        // 0..15 -> 4 output cols
    const int ty = tid >> 4;        // 0..15 -> 4 output rows
    const int r0 = blockIdx.y * TS;
    const int c0 = blockIdx.x * TS;

    float acc[4][4] = {};

    // staging indices: each thread loads one float4 of X and one of W per K-step
    const int lr = tid >> 2;            // 0..63 tile row
    const int lk = (tid & 3) * 4;       // 0,4,8,12
    const float* Xp = X + (size_t)(r0 + lr) * KD + lk;
    const float* Wp = W + (size_t)(c0 + lr) * KD + lk;

    for (int ks = 0; ks < KD; ks += KSTEP) {
        float4 xv = *(const float4*)(Xp + ks);
        float4 wv = *(const float4*)(Wp + ks);
        __syncthreads();
        Xs[lk + 0][lr] = xv.x; Xs[lk + 1][lr] = xv.y;
        Xs[lk + 2][lr] = xv.z; Xs[lk + 3][lr] = xv.w;
        Ws[lk + 0][lr] = wv.x; Ws[lk + 1][lr] = wv.y;
        Ws[lk + 2][lr] = wv.z; Ws[lk + 3][lr] = wv.w;
        __syncthreads();
#pragma unroll
        for (int kk = 0; kk < KSTEP; ++kk) {
            float4 a = *(const float4*)&Xs[kk][ty * 4];
            float4 b = *(const float4*)&Ws[kk][tx * 4];
            acc[0][0] += a.x * b.x; acc[0][1] += a.x * b.y; acc[0][2] += a.x * b.z; acc[0][3] += a.x * b.w;
            acc[1][0] += a.y * b.x; acc[1][1] += a.y * b.y; acc[1][2] += a.y * b.z; acc[1][3] += a.y * b.w;
            acc[2][0] += a.z * b.x; acc[2][1] += a.z * b.y; acc[2][2] += a.z * b.z; acc[2][3] += a.z * b.w;
            acc[3][0] += a.w * b.x; acc[3][1] += a.w * b.y; acc[3][2] += a.w * b.z; acc[3][3] += a.w * b.w;
        }
    }

    const int r = r0 + ty * 4;
    const int c = c0 + tx * 4;
#pragma unroll
    for (int i = 0; i < 4; ++i) {
#pragma unroll
        for (int j = 0; j < 4; ++j) {
            float v = acc[i][j] + bias[c + j];
            if (qkv_mode) {
                int cc = c + j, rr = r + i;
                int h = cc >> 6, d = cc & 63;
                int n = rr >> 11, s = rr & 2047;   // rr = n*2048 + s
                out[((size_t)((h << 1) | n) * SEQ + s) * HD + d] = v;
            } else {
                out[(size_t)(r + i) * DMODEL + (c + j)] = v;
            }
        }
    }
}

// ---------------------------------------------------------------------------
// Flash-style attention, fp32.
// q,k,v in ws laid out [H*N][S][64]. Output y_cat [N][S][H*64].
// One q-row per thread; 256 rows per block; K/V tiles of 32 rows in LDS.
// All compute-phase LDS reads are wave-uniform broadcasts (conflict-free).
// ---------------------------------------------------------------------------
__global__ __launch_bounds__(256) void attn_f32(
    const float* __restrict__ qp, const float* __restrict__ kp,
    const float* __restrict__ vp, float* __restrict__ yp)
{
    __shared__ float Ks[32][64];
    __shared__ float Vs[32][64];

    const int tid = threadIdx.x;
    const int hn = blockIdx.y;                 // h*2 + n
    const int r = blockIdx.x * 256 + tid;      // q row within (h,n)

    const float* qb = qp + ((size_t)hn * SEQ + r) * HD;
    float q[64];
#pragma unroll
    for (int i = 0; i < 16; ++i) {
        float4 t = *(const float4*)(qb + i * 4);
        q[i * 4 + 0] = t.x * 0.125f;   // fold 1/sqrt(64) into q
        q[i * 4 + 1] = t.y * 0.125f;
        q[i * 4 + 2] = t.z * 0.125f;
        q[i * 4 + 3] = t.w * 0.125f;
    }

    float o[64];
#pragma unroll
    for (int d = 0; d < 64; ++d) o[d] = 0.f;
    float m = -1e30f, sum = 0.f;

    const float* kb = kp + (size_t)hn * SEQ * HD;
    const float* vb = vp + (size_t)hn * SEQ * HD;

    const int lr = tid >> 3;           // 0..31
    const int lc = (tid & 7) * 8;      // 0..56

    for (int t0 = 0; t0 < SEQ; t0 += 32) {
        __syncthreads();
        {
            const float4* ksrc = (const float4*)(kb + ((size_t)(t0 + lr)) * HD + lc);
            const float4* vsrc = (const float4*)(vb + ((size_t)(t0 + lr)) * HD + lc);
            float4 a0 = ksrc[0], a1 = ksrc[1];
            float4 b0 = vsrc[0], b1 = vsrc[1];
            *(float4*)&Ks[lr][lc] = a0; *(float4*)&Ks[lr][lc + 4] = a1;
            *(float4*)&Vs[lr][lc] = b0; *(float4*)&Vs[lr][lc + 4] = b1;
        }
        __syncthreads();

        float s[32];
#pragma unroll
        for (int l = 0; l < 32; ++l) {
            float a0 = 0.f, a1 = 0.f, a2 = 0.f, a3 = 0.f;
#pragma unroll
            for (int d = 0; d < 64; d += 4) {
                a0 += q[d + 0] * Ks[l][d + 0];
                a1 += q[d + 1] * Ks[l][d + 1];
                a2 += q[d + 2] * Ks[l][d + 2];
                a3 += q[d + 3] * Ks[l][d + 3];
            }
            s[l] = (a0 + a1) + (a2 + a3);
        }

        float tmax = s[0];
#pragma unroll
        for (int l = 1; l < 32; ++l) tmax = fmaxf(tmax, s[l]);
        float mnew = fmaxf(m, tmax);
        float scale = __expf(m - mnew);
        m = mnew;
        sum *= scale;
#pragma unroll
        for (int d = 0; d < 64; ++d) o[d] *= scale;

#pragma unroll
        for (int l = 0; l < 32; ++l) {
            float p = __expf(s[l] - m);
            sum += p;
#pragma unroll
            for (int d = 0; d < 64; ++d) o[d] += p * Vs[l][d];
        }
    }

    const float inv = 1.f / sum;
    const int h = hn >> 1, n = hn & 1;
    float* yb = yp + ((size_t)(n * SEQ + r)) * DMODEL + h * HD;
#pragma unroll
    for (int i = 0; i < 16; ++i) {
        float4 t;
        t.x = o[i * 4 + 0] * inv; t.y = o[i * 4 + 1] * inv;
        t.z = o[i * 4 + 2] * inv; t.w = o[i * 4 + 3] * inv;
        *(float4*)(yb + i * 4) = t;
    }
}

// ---------------------------------------------------------------------------
extern "C" void kernel_launch(void* const* d_in, const int* in_sizes, int n_in,
                              void* d_out, int out_size, void* d_ws, size_t ws_size,
                              hipStream_t stream)
{
    const float* query = (const float*)d_in[0];
    const float* key_  = (const float*)d_in[1];
    const float* value = (const float*)d_in[2];
    const float* Wq = (const float*)d_in[3];
    const float* bq = (const float*)d_in[4];
    const float* Wk = (const float*)d_in[5];
    const float* bk = (const float*)d_in[6];
    const float* Wv = (const float*)d_in[7];
    const float* bv = (const float*)d_in[8];
    const float* Wo = (const float*)d_in[9];
    const float* bo = (const float*)d_in[10];
    float* out = (float*)d_out;

    // workspace: q,k,v [H*N][S][64] (16 MB each) + y_cat [N][S][1024] (16 MB)
    float* ws = (float*)d_ws;
    float* qp = ws;
    float* kp = ws + (size_t)4194304;
    float* vp = ws + (size_t)8388608;
    float* yp = ws + (size_t)12582912;

    dim3 gg(DMODEL / TS, (NB * SEQ) / TS);   // (16, 64)
    dim3 bb(256);

    gemm_xwT_f32<<<gg, bb, 0, stream>>>(query, Wq, bq, qp, 1);
    gemm_xwT_f32<<<gg, bb, 0, stream>>>(key_,  Wk, bk, kp, 1);
    gemm_xwT_f32<<<gg, bb, 0, stream>>>(value, Wv, bv, vp, 1);
    attn_f32<<<dim3(SEQ / 256, NH * NB), bb, 0, stream>>>(qp, kp, vp, yp);
    gemm_xwT_f32<<<gg, bb, 0, stream>>>(yp, Wo, bo, out, 0);
}

// Round 2
// 472.250 us; speedup vs baseline: 5.9856x; 5.9856x over previous
//
#include <hip/hip_runtime.h>
#include <hip/hip_bf16.h>

// N=2 batch, S=2048 seq, M=1024 d_model, H=16 heads, D=64 head dim
#define NB 2
#define SEQ 2048
#define DM 1024
#define NH 16
#define HD 64

typedef unsigned short u16;
typedef __attribute__((ext_vector_type(8))) short bf16x8;
typedef __attribute__((ext_vector_type(4))) float f32x4;
typedef __attribute__((ext_vector_type(4))) unsigned short u16x4;

#define MFMA __builtin_amdgcn_mfma_f32_16x16x32_bf16

__device__ __forceinline__ u16 bf16_rne(float x) {
    unsigned int u = __float_as_uint(x);
    return (u16)((u + 0x7FFFu + ((u >> 16) & 1u)) >> 16);
}
__device__ __forceinline__ float bf16f(u16 h) {
    return __uint_as_float(((unsigned int)h) << 16);
}
__device__ __forceinline__ void split2(float x, u16& h, u16& l) {
    h = bf16_rne(x);
    l = bf16_rne(x - bf16f(h));
}

// ---------------------------------------------------------------------------
// Split-bf16 MFMA GEMM: out = X * W^T + bias
// VAR 0: QKV fused over blockIdx.z (X,W fp32; convert during staging)
//        z=0: Q -> scatter bf16 hi/lo [hn][s][64], W&bias scaled by 0.125
//        z=1: K -> same scatter
//        z=2: V -> scatter TRANSPOSED [hn][64][s] (for attention PV B-frags)
// VAR 1: final projection (X = yh/yl bf16 pairs; W=Wo fp32; out fp32 + bo)
// Tile 128x128, BK=32, 4 waves each 64x64 (4x4 MFMA tiles), 3-term split.
// LDS row stride 40 u16 = 80 B: 16B-aligned rows, 2-way max bank alias.
// ---------------------------------------------------------------------------
template<int VAR>
__global__ __launch_bounds__(256, 2) void gemm_k(
    const float* xq, const float* xk, const float* xv,
    const u16* xh, const u16* xl,
    const float* wq, const float* wk, const float* wv,
    const float* bq, const float* bk, const float* bv,
    u16* qh, u16* ql, u16* kh, u16* kl, u16* vh, u16* vl,
    float* outf)
{
    __shared__ u16 XsH[128][40], XsL[128][40], WsH[128][40], WsL[128][40];

    const int tid = threadIdx.x;
    const int c0 = blockIdx.x * 128, r0 = blockIdx.y * 128;

    const float* xf = nullptr;
    const float* wf = nullptr;
    const float* bias = nullptr;
    u16 *oh = nullptr, *ol = nullptr;
    float wsc = 1.f, bsc = 1.f;
    int mode = 0;
    if (VAR == 0) {
        const int z = blockIdx.z;
        if (z == 0)      { xf = xq; wf = wq; bias = bq; oh = qh; ol = ql; wsc = 0.125f; bsc = 0.125f; mode = 1; }
        else if (z == 1) { xf = xk; wf = wk; bias = bk; oh = kh; ol = kl; mode = 1; }
        else             { xf = xv; wf = wv; bias = bv; oh = vh; ol = vl; mode = 2; }
    } else {
        wf = wq; bias = bq; mode = 0;   // arg slots reused: wq=Wo, bq=bo
    }

    const int lane = tid & 63, w = tid >> 6;
    const int wr = (w >> 1) * 64, wc = (w & 1) * 64;
    const int lg = lane >> 4, lc = lane & 15;

    f32x4 acc[4][4];
#pragma unroll
    for (int i = 0; i < 4; ++i)
#pragma unroll
        for (int j = 0; j < 4; ++j) acc[i][j] = (f32x4)0.f;

    for (int ks = 0; ks < DM; ks += 32) {
        __syncthreads();
        if (VAR == 0) {
#pragma unroll
            for (int i = 0; i < 4; ++i) {
                int f = tid + 256 * i, row = f >> 3, kq = (f & 7) * 4;
                float4 v = *(const float4*)(xf + (size_t)(r0 + row) * DM + ks + kq);
                u16 h0, h1, h2, h3, l0, l1, l2, l3;
                split2(v.x, h0, l0); split2(v.y, h1, l1);
                split2(v.z, h2, l2); split2(v.w, h3, l3);
                u16x4 hv = {h0, h1, h2, h3}, lv = {l0, l1, l2, l3};
                *(u16x4*)&XsH[row][kq] = hv;
                *(u16x4*)&XsL[row][kq] = lv;
            }
        } else {
#pragma unroll
            for (int i = 0; i < 2; ++i) {
                int f = tid + 256 * i, row = f >> 2, kb = (f & 3) * 8;
                *(bf16x8*)&XsH[row][kb] = *(const bf16x8*)(xh + (size_t)(r0 + row) * DM + ks + kb);
                *(bf16x8*)&XsL[row][kb] = *(const bf16x8*)(xl + (size_t)(r0 + row) * DM + ks + kb);
            }
        }
#pragma unroll
        for (int i = 0; i < 4; ++i) {
            int f = tid + 256 * i, row = f >> 3, kq = (f & 7) * 4;
            float4 v = *(const float4*)(wf + (size_t)(c0 + row) * DM + ks + kq);
            v.x *= wsc; v.y *= wsc; v.z *= wsc; v.w *= wsc;
            u16 h0, h1, h2, h3, l0, l1, l2, l3;
            split2(v.x, h0, l0); split2(v.y, h1, l1);
            split2(v.z, h2, l2); split2(v.w, h3, l3);
            u16x4 hv = {h0, h1, h2, h3}, lv = {l0, l1, l2, l3};
            *(u16x4*)&WsH[row][kq] = hv;
            *(u16x4*)&WsL[row][kq] = lv;
        }
        __syncthreads();

        bf16x8 ah[4], al[4];
#pragma unroll
        for (int rt = 0; rt < 4; ++rt) {
            ah[rt] = *(const bf16x8*)&XsH[wr + rt * 16 + lc][lg * 8];
            al[rt] = *(const bf16x8*)&XsL[wr + rt * 16 + lc][lg * 8];
        }
#pragma unroll
        for (int jt = 0; jt < 4; ++jt) {
            bf16x8 bh2 = *(const bf16x8*)&WsH[wc + jt * 16 + lc][lg * 8];
            bf16x8 bl2 = *(const bf16x8*)&WsL[wc + jt * 16 + lc][lg * 8];
#pragma unroll
            for (int rt = 0; rt < 4; ++rt) {
                acc[rt][jt] = MFMA(ah[rt], bh2, acc[rt][jt], 0, 0, 0);
                acc[rt][jt] = MFMA(ah[rt], bl2, acc[rt][jt], 0, 0, 0);
                acc[rt][jt] = MFMA(al[rt], bh2, acc[rt][jt], 0, 0, 0);
            }
        }
    }

#pragma unroll
    for (int rt = 0; rt < 4; ++rt)
#pragma unroll
        for (int jt = 0; jt < 4; ++jt)
#pragma unroll
            for (int r = 0; r < 4; ++r) {
                int row = r0 + wr + rt * 16 + lg * 4 + r;
                int col = c0 + wc + jt * 16 + lc;
                float v = acc[rt][jt][r] + bias[col] * bsc;
                if (mode == 0) {
                    outf[(size_t)row * DM + col] = v;
                } else if (mode == 1) {
                    int h = col >> 6, d = col & 63, n = row >> 11, s = row & 2047;
                    size_t idx = ((size_t)((h << 1) | n) * SEQ + s) * HD + d;
                    u16 hh, ll; split2(v, hh, ll);
                    oh[idx] = hh; ol[idx] = ll;
                } else {
                    int h = col >> 6, d = col & 63, n = row >> 11, s = row & 2047;
                    size_t idx = ((size_t)((h << 1) | n) * HD + d) * SEQ + s;
                    u16 hh, ll; split2(v, hh, ll);
                    oh[idx] = hh; ol[idx] = ll;
                }
            }
}

// ---------------------------------------------------------------------------
// Flash attention, split-bf16 MFMA.
// Block: 4 waves x 32 q-rows = 128 rows of one (h,n). Grid (16, 32).
// K/V tiles of 64 staged in LDS (K row-major [64][64], V transposed [64 d][64 s],
// both hi/lo, row stride 72 u16 = 144 B -> 16B-aligned, 2-way max alias).
// QK^T: 3-term split (q,k hi/lo). Softmax in D-layout registers; P (plain
// bf16) bounced via per-wave LDS buffer to A-fragment layout. PV: 2-term
// (p plain, v hi/lo). Online softmax: per-tile cross-lane max reduce;
// per-lane partial sums reduced once at the end.
// ---------------------------------------------------------------------------
__global__ __launch_bounds__(256, 2) void attn_k(
    const u16* __restrict__ qh, const u16* __restrict__ ql,
    const u16* __restrict__ kh, const u16* __restrict__ kl,
    const u16* __restrict__ vth, const u16* __restrict__ vtl,
    u16* __restrict__ yh, u16* __restrict__ yl)
{
    __shared__ u16 KsH[64][72], KsL[64][72], VsH[64][72], VsL[64][72];
    __shared__ u16 Pb[4][32][72];

    const int tid = threadIdx.x, lane = tid & 63, w = tid >> 6;
    const int hn = blockIdx.y;
    const int qb0 = blockIdx.x * 128;
    const int lg = lane >> 4, lc = lane & 15;

    // Q fragments (hi/lo), resident in registers for the whole kernel
    bf16x8 qfh[2][2], qfl[2][2];
    const size_t qkbase = (size_t)hn * SEQ * HD;
#pragma unroll
    for (int rt = 0; rt < 2; ++rt)
#pragma unroll
        for (int kc = 0; kc < 2; ++kc) {
            size_t off = qkbase + (size_t)(qb0 + w * 32 + rt * 16 + lc) * HD + kc * 32 + lg * 8;
            qfh[rt][kc] = *(const bf16x8*)(qh + off);
            qfl[rt][kc] = *(const bf16x8*)(ql + off);
        }

    f32x4 acc_o[2][4];
#pragma unroll
    for (int i = 0; i < 2; ++i)
#pragma unroll
        for (int j = 0; j < 4; ++j) acc_o[i][j] = (f32x4)0.f;
    float m_[2][4], s_[2][4];
#pragma unroll
    for (int i = 0; i < 2; ++i)
#pragma unroll
        for (int r = 0; r < 4; ++r) { m_[i][r] = -3e38f; s_[i][r] = 0.f; }

    const size_t vbase = (size_t)hn * HD * SEQ;

    for (int kt = 0; kt < SEQ; kt += 64) {
        __syncthreads();
#pragma unroll
        for (int i = 0; i < 2; ++i) {
            int f = tid + 256 * i, row = f >> 3, kb = (f & 7) * 8;
            size_t ksrc = qkbase + (size_t)(kt + row) * HD + kb;
            *(bf16x8*)&KsH[row][kb] = *(const bf16x8*)(kh + ksrc);
            *(bf16x8*)&KsL[row][kb] = *(const bf16x8*)(kl + ksrc);
            size_t vsrc = vbase + (size_t)row * SEQ + kt + kb;   // row = d
            *(bf16x8*)&VsH[row][kb] = *(const bf16x8*)(vth + vsrc);
            *(bf16x8*)&VsL[row][kb] = *(const bf16x8*)(vtl + vsrc);
        }
        __syncthreads();

        // ---- QK^T (3-term split) ----
        f32x4 sc[2][4];
#pragma unroll
        for (int i = 0; i < 2; ++i)
#pragma unroll
            for (int j = 0; j < 4; ++j) sc[i][j] = (f32x4)0.f;
#pragma unroll
        for (int jt = 0; jt < 4; ++jt)
#pragma unroll
            for (int kc = 0; kc < 2; ++kc) {
                bf16x8 bh2 = *(const bf16x8*)&KsH[jt * 16 + lc][kc * 32 + lg * 8];
                bf16x8 bl2 = *(const bf16x8*)&KsL[jt * 16 + lc][kc * 32 + lg * 8];
#pragma unroll
                for (int rt = 0; rt < 2; ++rt) {
                    sc[rt][jt] = MFMA(qfh[rt][kc], bh2, sc[rt][jt], 0, 0, 0);
                    sc[rt][jt] = MFMA(qfh[rt][kc], bl2, sc[rt][jt], 0, 0, 0);
                    sc[rt][jt] = MFMA(qfl[rt][kc], bh2, sc[rt][jt], 0, 0, 0);
                }
            }

        // ---- online softmax (rows live at (lg*4+r), cols at lc) ----
#pragma unroll
        for (int rt = 0; rt < 2; ++rt)
#pragma unroll
            for (int r = 0; r < 4; ++r) {
                float v = fmaxf(fmaxf(sc[rt][0][r], sc[rt][1][r]),
                                fmaxf(sc[rt][2][r], sc[rt][3][r]));
                v = fmaxf(v, __shfl_xor(v, 1));
                v = fmaxf(v, __shfl_xor(v, 2));
                v = fmaxf(v, __shfl_xor(v, 4));
                v = fmaxf(v, __shfl_xor(v, 8));
                float mnew = fmaxf(m_[rt][r], v);
                float resc = __expf(m_[rt][r] - mnew);
                m_[rt][r] = mnew;
                s_[rt][r] *= resc;
#pragma unroll
                for (int dt = 0; dt < 4; ++dt) acc_o[rt][dt][r] *= resc;
            }
#pragma unroll
        for (int rt = 0; rt < 2; ++rt)
#pragma unroll
            for (int jt = 0; jt < 4; ++jt)
#pragma unroll
                for (int r = 0; r < 4; ++r) {
                    float p = __expf(sc[rt][jt][r] - m_[rt][r]);
                    s_[rt][r] += p;
                    Pb[w][rt * 16 + lg * 4 + r][jt * 16 + lc] = bf16_rne(p);
                }

        // ---- PV (p plain bf16, v hi/lo) ----
        bf16x8 pa[2][2];
#pragma unroll
        for (int rt = 0; rt < 2; ++rt)
#pragma unroll
            for (int jc = 0; jc < 2; ++jc)
                pa[rt][jc] = *(const bf16x8*)&Pb[w][rt * 16 + lc][jc * 32 + lg * 8];
#pragma unroll
        for (int dt = 0; dt < 4; ++dt)
#pragma unroll
            for (int jc = 0; jc < 2; ++jc) {
                bf16x8 vh8 = *(const bf16x8*)&VsH[dt * 16 + lc][jc * 32 + lg * 8];
                bf16x8 vl8 = *(const bf16x8*)&VsL[dt * 16 + lc][jc * 32 + lg * 8];
#pragma unroll
                for (int rt = 0; rt < 2; ++rt) {
                    acc_o[rt][dt] = MFMA(pa[rt][jc], vh8, acc_o[rt][dt], 0, 0, 0);
                    acc_o[rt][dt] = MFMA(pa[rt][jc], vl8, acc_o[rt][dt], 0, 0, 0);
                }
            }
    }

    // ---- epilogue: reduce partial sums across the 16 col-lanes, write y ----
    const int h = hn >> 1, n = hn & 1;
#pragma unroll
    for (int rt = 0; rt < 2; ++rt)
#pragma unroll
        for (int r = 0; r < 4; ++r) {
            float v = s_[rt][r];
            v += __shfl_xor(v, 1);
            v += __shfl_xor(v, 2);
            v += __shfl_xor(v, 4);
            v += __shfl_xor(v, 8);
            s_[rt][r] = 1.f / v;
        }
#pragma unroll
    for (int rt = 0; rt < 2; ++rt)
#pragma unroll
        for (int dt = 0; dt < 4; ++dt)
#pragma unroll
            for (int r = 0; r < 4; ++r) {
                float y = acc_o[rt][dt][r] * s_[rt][r];
                int srow = qb0 + w * 32 + rt * 16 + lg * 4 + r;
                size_t idx = (size_t)(n * SEQ + srow) * DM + h * HD + dt * 16 + lc;
                u16 hh, ll; split2(y, hh, ll);
                yh[idx] = hh; yl[idx] = ll;
            }
}

// ---------------------------------------------------------------------------
extern "C" void kernel_launch(void* const* d_in, const int* in_sizes, int n_in,
                              void* d_out, int out_size, void* d_ws, size_t ws_size,
                              hipStream_t stream)
{
    const float* query = (const float*)d_in[0];
    const float* key_  = (const float*)d_in[1];
    const float* value = (const float*)d_in[2];
    const float* Wq = (const float*)d_in[3];
    const float* bq = (const float*)d_in[4];
    const float* Wk = (const float*)d_in[5];
    const float* bk = (const float*)d_in[6];
    const float* Wv = (const float*)d_in[7];
    const float* bv = (const float*)d_in[8];
    const float* Wo = (const float*)d_in[9];
    const float* bo = (const float*)d_in[10];
    float* out = (float*)d_out;

    // ws: 8 bf16 regions of 4,194,304 elements (8 MiB) = 64 MiB total
    char* ws = (char*)d_ws;
    u16* qh  = (u16*)(ws);
    u16* ql  = (u16*)(ws + 8388608ull);
    u16* kh  = (u16*)(ws + 16777216ull);
    u16* kl  = (u16*)(ws + 25165824ull);
    u16* vth = (u16*)(ws + 33554432ull);
    u16* vtl = (u16*)(ws + 41943040ull);
    u16* yh  = (u16*)(ws + 50331648ull);
    u16* yl  = (u16*)(ws + 58720256ull);

    gemm_k<0><<<dim3(8, 32, 3), 256, 0, stream>>>(
        query, key_, value, nullptr, nullptr,
        Wq, Wk, Wv, bq, bk, bv,
        qh, ql, kh, kl, vth, vtl, nullptr);

    attn_k<<<dim3(16, 32), 256, 0, stream>>>(qh, ql, kh, kl, vth, vtl, yh, yl);

    gemm_k<1><<<dim3(8, 32, 1), 256, 0, stream>>>(
        nullptr, nullptr, nullptr, yh, yl,
        Wo, nullptr, nullptr, bo, nullptr, nullptr,
        nullptr, nullptr, nullptr, nullptr, nullptr, nullptr, out);
}

// Round 3
// 392.594 us; speedup vs baseline: 7.2001x; 1.2029x over previous
//
#include <hip/hip_runtime.h>
#include <hip/hip_bf16.h>

// N=2 batch, S=2048 seq, M=1024 d_model, H=16 heads, D=64 head dim
#define NB 2
#define SEQ 2048
#define DM 1024
#define NH 16
#define HD 64

typedef unsigned short u16;
typedef unsigned int u32;
typedef __attribute__((ext_vector_type(8))) short bf16x8;
typedef __attribute__((ext_vector_type(4))) float f32x4;
typedef __attribute__((ext_vector_type(4))) unsigned short u16x4;

#define MFMA __builtin_amdgcn_mfma_f32_16x16x32_bf16

__device__ __forceinline__ u16 bf16_rne(float x) {
    unsigned int u = __float_as_uint(x);
    return (u16)((u + 0x7FFFu + ((u >> 16) & 1u)) >> 16);
}
__device__ __forceinline__ float bf16f(u16 h) {
    return __uint_as_float(((unsigned int)h) << 16);
}
__device__ __forceinline__ void split2(float x, u16& h, u16& l) {
    h = bf16_rne(x);
    l = bf16_rne(x - bf16f(h));
}

// async global->LDS, 16B per lane. LDS dest = wave-uniform base + lane*16.
__device__ __forceinline__ void async16(const u16* g, u16* l) {
    typedef const __attribute__((address_space(1))) u32* GP;
    typedef __attribute__((address_space(3))) u32* LP;
    __builtin_amdgcn_global_load_lds((GP)g, (LP)l, 16, 0, 0);
}

// ---------------------------------------------------------------------------
// Pre-split pass: fp32 -> (hi bf16, lo bf16), once per element.
// seg 0..2: query/key/value [4096][1024]; seg 3..6: Wq/Wk/Wv/Wo [1024][1024].
// Wq folded with 0.125 (the 1/sqrt(D) attention scale).
// ---------------------------------------------------------------------------
__global__ __launch_bounds__(256) void presplit(
    const float* __restrict__ x0, const float* __restrict__ x1,
    const float* __restrict__ x2, const float* __restrict__ wq,
    const float* __restrict__ wk, const float* __restrict__ wv,
    const float* __restrict__ wo,
    u16* __restrict__ xh, u16* __restrict__ xl,
    u16* __restrict__ wh, u16* __restrict__ wl)
{
    const int seg = blockIdx.y;
    const float* src;
    u16 *dh, *dl;
    int n4;
    float sc = 1.f;
    if (seg < 3) {
        src = (seg == 0) ? x0 : (seg == 1) ? x1 : x2;
        dh = xh + (size_t)seg * 4194304;
        dl = xl + (size_t)seg * 4194304;
        n4 = 1048576;
    } else {
        int s2 = seg - 3;
        src = (s2 == 0) ? wq : (s2 == 1) ? wk : (s2 == 2) ? wv : wo;
        dh = wh + (size_t)s2 * 1048576;
        dl = wl + (size_t)s2 * 1048576;
        n4 = 262144;
        if (s2 == 0) sc = 0.125f;
    }
    for (int i = blockIdx.x * 256 + threadIdx.x; i < n4; i += gridDim.x * 256) {
        float4 v = ((const float4*)src)[i];
        u16 h0, h1, h2, h3, l0, l1, l2, l3;
        split2(v.x * sc, h0, l0); split2(v.y * sc, h1, l1);
        split2(v.z * sc, h2, l2); split2(v.w * sc, h3, l3);
        u16x4 hv = {h0, h1, h2, h3}, lv = {l0, l1, l2, l3};
        *(u16x4*)(dh + (size_t)i * 4) = hv;
        *(u16x4*)(dl + (size_t)i * 4) = lv;
    }
}

// ---------------------------------------------------------------------------
// Split-bf16 MFMA GEMM (m97 structure): out = X * W^T + bias
// 128x128 tile, BK=32, 4 waves (64x64 each), global_load_lds width-16
// staging (wave w owns array w of {Ah,Al,Bh,Bl}), linear LDS [128][32].
// 3-term split product per fragment pair. XCD-aware block swizzle.
// VAR 0: QKV fused over z. z=0 Q scatter hi/lo [hn][s][64] (bias*0.125);
//        z=1 K same; z=2 V scatter transposed [hn][64][s].
// VAR 1: final projection, fp32 out + bo.
// ---------------------------------------------------------------------------
template<int VAR>
__global__ __launch_bounds__(256, 2) void gemm2(
    const u16* __restrict__ xh3, const u16* __restrict__ xl3,
    const u16* __restrict__ wh4, const u16* __restrict__ wl4,
    const float* bq, const float* bk, const float* bv,
    u16* qh, u16* ql, u16* kh, u16* kl, u16* vh, u16* vl,
    float* outf)
{
    __shared__ u16 Ah[128][32], Al[128][32], Bh[128][32], Bl[128][32];

    const int tid = threadIdx.x, lane = tid & 63, w = tid >> 6;
    const int lg = lane >> 4, lc = lane & 15;

    // XCD swizzle: 256 blocks per z, 8 XCDs -> same-XCD blocks get
    // consecutive tiles (bx fastest) -> A-panel L2 reuse.
    const int id = blockIdx.x + 8 * blockIdx.y;
    const int swz = (id & 7) * 32 + (id >> 3);
    const int c0 = (swz & 7) * 128, r0 = (swz >> 3) * 128;

    const u16 *ag, *alg, *bg, *blg;
    const float* bias;
    u16 *oh = nullptr, *ol = nullptr;
    float bsc = 1.f;
    int mode;
    if (VAR == 0) {
        const int z = blockIdx.z;
        ag  = xh3 + (size_t)z * 4194304;
        alg = xl3 + (size_t)z * 4194304;
        bg  = wh4 + (size_t)z * 1048576;
        blg = wl4 + (size_t)z * 1048576;
        if (z == 0)      { bias = bq; oh = qh; ol = ql; bsc = 0.125f; mode = 1; }
        else if (z == 1) { bias = bk; oh = kh; ol = kl; mode = 1; }
        else             { bias = bv; oh = vh; ol = vl; mode = 2; }
    } else {
        ag = xh3; alg = xl3; bg = wh4; blg = wl4; bias = bq; mode = 0;
    }

    // staging role: wave w stages array w (8 chunks of 1KB each)
    const u16* gb = (w == 0) ? ag : (w == 1) ? alg : (w == 2) ? bg : blg;
    u16* lb = (w == 0) ? &Ah[0][0] : (w == 1) ? &Al[0][0] : (w == 2) ? &Bh[0][0] : &Bl[0][0];
    const int rbase = (w < 2) ? r0 : c0;
    const u16* gsrc0 = gb + (size_t)(rbase + (lane >> 2)) * DM + (lane & 3) * 8;

    const int wr = (w >> 1) * 64, wc = (w & 1) * 64;

    f32x4 acc[4][4];
#pragma unroll
    for (int i = 0; i < 4; ++i)
#pragma unroll
        for (int j = 0; j < 4; ++j) acc[i][j] = (f32x4)0.f;

    for (int ks = 0; ks < DM; ks += 32) {
        __syncthreads();
#pragma unroll
        for (int i = 0; i < 8; ++i)
            async16(gsrc0 + (size_t)i * 16 * DM + ks, lb + i * 512);
        __syncthreads();

        bf16x8 ah[4], al[4];
#pragma unroll
        for (int rt = 0; rt < 4; ++rt) {
            ah[rt] = *(const bf16x8*)&Ah[wr + rt * 16 + lc][lg * 8];
            al[rt] = *(const bf16x8*)&Al[wr + rt * 16 + lc][lg * 8];
        }
#pragma unroll
        for (int jt = 0; jt < 4; ++jt) {
            bf16x8 bh2 = *(const bf16x8*)&Bh[wc + jt * 16 + lc][lg * 8];
            bf16x8 bl2 = *(const bf16x8*)&Bl[wc + jt * 16 + lc][lg * 8];
#pragma unroll
            for (int rt = 0; rt < 4; ++rt) {
                acc[rt][jt] = MFMA(ah[rt], bh2, acc[rt][jt], 0, 0, 0);
                acc[rt][jt] = MFMA(ah[rt], bl2, acc[rt][jt], 0, 0, 0);
                acc[rt][jt] = MFMA(al[rt], bh2, acc[rt][jt], 0, 0, 0);
            }
        }
    }

#pragma unroll
    for (int rt = 0; rt < 4; ++rt)
#pragma unroll
        for (int jt = 0; jt < 4; ++jt)
#pragma unroll
            for (int r = 0; r < 4; ++r) {
                int row = r0 + wr + rt * 16 + lg * 4 + r;
                int col = c0 + wc + jt * 16 + lc;
                float v = acc[rt][jt][r] + bias[col] * bsc;
                if (mode == 0) {
                    outf[(size_t)row * DM + col] = v;
                } else if (mode == 1) {
                    int h = col >> 6, d = col & 63, n = row >> 11, s = row & 2047;
                    size_t idx = ((size_t)((h << 1) | n) * SEQ + s) * HD + d;
                    u16 hh, ll; split2(v, hh, ll);
                    oh[idx] = hh; ol[idx] = ll;
                } else {
                    int h = col >> 6, d = col & 63, n = row >> 11, s = row & 2047;
                    size_t idx = ((size_t)((h << 1) | n) * HD + d) * SEQ + s;
                    u16 hh, ll; split2(v, hh, ll);
                    oh[idx] = hh; ol[idx] = ll;
                }
            }
}

// ---------------------------------------------------------------------------
// Flash attention, split-bf16 MFMA (unchanged from round 2 — proven).
// ---------------------------------------------------------------------------
__global__ __launch_bounds__(256, 2) void attn_k(
    const u16* __restrict__ qh, const u16* __restrict__ ql,
    const u16* __restrict__ kh, const u16* __restrict__ kl,
    const u16* __restrict__ vth, const u16* __restrict__ vtl,
    u16* __restrict__ yh, u16* __restrict__ yl)
{
    __shared__ u16 KsH[64][72], KsL[64][72], VsH[64][72], VsL[64][72];
    __shared__ u16 Pb[4][32][72];

    const int tid = threadIdx.x, lane = tid & 63, w = tid >> 6;
    const int hn = blockIdx.y;
    const int qb0 = blockIdx.x * 128;
    const int lg = lane >> 4, lc = lane & 15;

    bf16x8 qfh[2][2], qfl[2][2];
    const size_t qkbase = (size_t)hn * SEQ * HD;
#pragma unroll
    for (int rt = 0; rt < 2; ++rt)
#pragma unroll
        for (int kc = 0; kc < 2; ++kc) {
            size_t off = qkbase + (size_t)(qb0 + w * 32 + rt * 16 + lc) * HD + kc * 32 + lg * 8;
            qfh[rt][kc] = *(const bf16x8*)(qh + off);
            qfl[rt][kc] = *(const bf16x8*)(ql + off);
        }

    f32x4 acc_o[2][4];
#pragma unroll
    for (int i = 0; i < 2; ++i)
#pragma unroll
        for (int j = 0; j < 4; ++j) acc_o[i][j] = (f32x4)0.f;
    float m_[2][4], s_[2][4];
#pragma unroll
    for (int i = 0; i < 2; ++i)
#pragma unroll
        for (int r = 0; r < 4; ++r) { m_[i][r] = -3e38f; s_[i][r] = 0.f; }

    const size_t vbase = (size_t)hn * HD * SEQ;

    for (int kt = 0; kt < SEQ; kt += 64) {
        __syncthreads();
#pragma unroll
        for (int i = 0; i < 2; ++i) {
            int f = tid + 256 * i, row = f >> 3, kb = (f & 7) * 8;
            size_t ksrc = qkbase + (size_t)(kt + row) * HD + kb;
            *(bf16x8*)&KsH[row][kb] = *(const bf16x8*)(kh + ksrc);
            *(bf16x8*)&KsL[row][kb] = *(const bf16x8*)(kl + ksrc);
            size_t vsrc = vbase + (size_t)row * SEQ + kt + kb;
            *(bf16x8*)&VsH[row][kb] = *(const bf16x8*)(vth + vsrc);
            *(bf16x8*)&VsL[row][kb] = *(const bf16x8*)(vtl + vsrc);
        }
        __syncthreads();

        f32x4 sc[2][4];
#pragma unroll
        for (int i = 0; i < 2; ++i)
#pragma unroll
            for (int j = 0; j < 4; ++j) sc[i][j] = (f32x4)0.f;
#pragma unroll
        for (int jt = 0; jt < 4; ++jt)
#pragma unroll
            for (int kc = 0; kc < 2; ++kc) {
                bf16x8 bh2 = *(const bf16x8*)&KsH[jt * 16 + lc][kc * 32 + lg * 8];
                bf16x8 bl2 = *(const bf16x8*)&KsL[jt * 16 + lc][kc * 32 + lg * 8];
#pragma unroll
                for (int rt = 0; rt < 2; ++rt) {
                    sc[rt][jt] = MFMA(qfh[rt][kc], bh2, sc[rt][jt], 0, 0, 0);
                    sc[rt][jt] = MFMA(qfh[rt][kc], bl2, sc[rt][jt], 0, 0, 0);
                    sc[rt][jt] = MFMA(qfl[rt][kc], bh2, sc[rt][jt], 0, 0, 0);
                }
            }

#pragma unroll
        for (int rt = 0; rt < 2; ++rt)
#pragma unroll
            for (int r = 0; r < 4; ++r) {
                float v = fmaxf(fmaxf(sc[rt][0][r], sc[rt][1][r]),
                                fmaxf(sc[rt][2][r], sc[rt][3][r]));
                v = fmaxf(v, __shfl_xor(v, 1));
                v = fmaxf(v, __shfl_xor(v, 2));
                v = fmaxf(v, __shfl_xor(v, 4));
                v = fmaxf(v, __shfl_xor(v, 8));
                float mnew = fmaxf(m_[rt][r], v);
                float resc = __expf(m_[rt][r] - mnew);
                m_[rt][r] = mnew;
                s_[rt][r] *= resc;
#pragma unroll
                for (int dt = 0; dt < 4; ++dt) acc_o[rt][dt][r] *= resc;
            }
#pragma unroll
        for (int rt = 0; rt < 2; ++rt)
#pragma unroll
            for (int jt = 0; jt < 4; ++jt)
#pragma unroll
                for (int r = 0; r < 4; ++r) {
                    float p = __expf(sc[rt][jt][r] - m_[rt][r]);
                    s_[rt][r] += p;
                    Pb[w][rt * 16 + lg * 4 + r][jt * 16 + lc] = bf16_rne(p);
                }

        bf16x8 pa[2][2];
#pragma unroll
        for (int rt = 0; rt < 2; ++rt)
#pragma unroll
            for (int jc = 0; jc < 2; ++jc)
                pa[rt][jc] = *(const bf16x8*)&Pb[w][rt * 16 + lc][jc * 32 + lg * 8];
#pragma unroll
        for (int dt = 0; dt < 4; ++dt)
#pragma unroll
            for (int jc = 0; jc < 2; ++jc) {
                bf16x8 vh8 = *(const bf16x8*)&VsH[dt * 16 + lc][jc * 32 + lg * 8];
                bf16x8 vl8 = *(const bf16x8*)&VsL[dt * 16 + lc][jc * 32 + lg * 8];
#pragma unroll
                for (int rt = 0; rt < 2; ++rt) {
                    acc_o[rt][dt] = MFMA(pa[rt][jc], vh8, acc_o[rt][dt], 0, 0, 0);
                    acc_o[rt][dt] = MFMA(pa[rt][jc], vl8, acc_o[rt][dt], 0, 0, 0);
                }
            }
    }

    const int h = hn >> 1, n = hn & 1;
#pragma unroll
    for (int rt = 0; rt < 2; ++rt)
#pragma unroll
        for (int r = 0; r < 4; ++r) {
            float v = s_[rt][r];
            v += __shfl_xor(v, 1);
            v += __shfl_xor(v, 2);
            v += __shfl_xor(v, 4);
            v += __shfl_xor(v, 8);
            s_[rt][r] = 1.f / v;
        }
#pragma unroll
    for (int rt = 0; rt < 2; ++rt)
#pragma unroll
        for (int dt = 0; dt < 4; ++dt)
#pragma unroll
            for (int r = 0; r < 4; ++r) {
                float y = acc_o[rt][dt][r] * s_[rt][r];
                int srow = qb0 + w * 32 + rt * 16 + lg * 4 + r;
                size_t idx = (size_t)(n * SEQ + srow) * DM + h * HD + dt * 16 + lc;
                u16 hh, ll; split2(y, hh, ll);
                yh[idx] = hh; yl[idx] = ll;
            }
}

// ---------------------------------------------------------------------------
extern "C" void kernel_launch(void* const* d_in, const int* in_sizes, int n_in,
                              void* d_out, int out_size, void* d_ws, size_t ws_size,
                              hipStream_t stream)
{
    const float* query = (const float*)d_in[0];
    const float* key_  = (const float*)d_in[1];
    const float* value = (const float*)d_in[2];
    const float* Wq = (const float*)d_in[3];
    const float* bq = (const float*)d_in[4];
    const float* Wk = (const float*)d_in[5];
    const float* bk = (const float*)d_in[6];
    const float* Wv = (const float*)d_in[7];
    const float* bv = (const float*)d_in[8];
    const float* Wo = (const float*)d_in[9];
    const float* bo = (const float*)d_in[10];
    float* out = (float*)d_out;

    // ws map (112 MiB):
    //   0MB  wh[4]   (8MB)     8MB  wl[4]   (8MB)
    //  16MB  qh ql kh kl vth vtl  (6 x 8MB = 48MB)
    //  64MB  xh[3]  (24MB)  -- reused after QKV: yh @64MB, yl @72MB
    //  88MB  xl[3]  (24MB)
    char* p = (char*)d_ws;
    u16* wh  = (u16*)(p);
    u16* wl  = (u16*)(p + 8388608ull);
    u16* qh  = (u16*)(p + 16777216ull);
    u16* ql  = (u16*)(p + 25165824ull);
    u16* kh  = (u16*)(p + 33554432ull);
    u16* kl  = (u16*)(p + 41943040ull);
    u16* vth = (u16*)(p + 50331648ull);
    u16* vtl = (u16*)(p + 58720256ull);
    u16* xh  = (u16*)(p + 67108864ull);
    u16* xl  = (u16*)(p + 92274688ull);
    u16* yh  = (u16*)(p + 67108864ull);
    u16* yl  = (u16*)(p + 75497472ull);

    presplit<<<dim3(256, 7), 256, 0, stream>>>(
        query, key_, value, Wq, Wk, Wv, Wo, xh, xl, wh, wl);

    gemm2<0><<<dim3(8, 32, 3), 256, 0, stream>>>(
        xh, xl, wh, wl, bq, bk, bv,
        qh, ql, kh, kl, vth, vtl, nullptr);

    attn_k<<<dim3(16, 32), 256, 0, stream>>>(qh, ql, kh, kl, vth, vtl, yh, yl);

    gemm2<1><<<dim3(8, 32, 1), 256, 0, stream>>>(
        yh, yl, wh + 3145728ull, wl + 3145728ull, bo, nullptr, nullptr,
        nullptr, nullptr, nullptr, nullptr, nullptr, nullptr, out);
}

// Round 5
// 368.124 us; speedup vs baseline: 7.6787x; 1.0665x over previous
//
#include <hip/hip_runtime.h>
#include <hip/hip_bf16.h>

// N=2 batch, S=2048 seq, M=1024 d_model, H=16 heads, D=64 head dim
#define NB 2
#define SEQ 2048
#define DM 1024
#define NH 16
#define HD 64

typedef unsigned short u16;
typedef unsigned int u32;
typedef __attribute__((ext_vector_type(8))) short bf16x8;
typedef __attribute__((ext_vector_type(4))) float f32x4;
typedef __attribute__((ext_vector_type(4))) unsigned short u16x4;
typedef __attribute__((ext_vector_type(2))) unsigned int u32x2;

#define MFMA __builtin_amdgcn_mfma_f32_16x16x32_bf16

// log2(e) * 0.125  (attention scale folded with exp2 conversion)
#define QSCALE 0.18033688011112042f

__device__ __forceinline__ u16 bf16_rne(float x) {
    unsigned int u = __float_as_uint(x);
    return (u16)((u + 0x7FFFu + ((u >> 16) & 1u)) >> 16);
}
__device__ __forceinline__ float bf16f(u16 h) {
    return __uint_as_float(((unsigned int)h) << 16);
}
__device__ __forceinline__ void split2(float x, u16& h, u16& l) {
    h = bf16_rne(x);
    l = bf16_rne(x - bf16f(h));
}
// packed 2xf32 -> 2xbf16 (RNE), one instruction
__device__ __forceinline__ u32 cvt_pk_bf16(float lo, float hi) {
    u32 r;
    asm("v_cvt_pk_bf16_f32 %0, %1, %2" : "=v"(r) : "v"(lo), "v"(hi));
    return r;
}
// 2^x on the transcendental pipe
__device__ __forceinline__ float exp2_fast(float x) {
#if __has_builtin(__builtin_amdgcn_exp2f)
    return __builtin_amdgcn_exp2f(x);
#else
    float r;
    asm("v_exp_f32 %0, %1" : "=v"(r) : "v"(x));
    return r;
#endif
}

// async global->LDS, 16B per lane. LDS dest = wave-uniform base + lane*16.
__device__ __forceinline__ void async16(const u16* g, u16* l) {
    typedef const __attribute__((address_space(1))) u32* GP;
    typedef __attribute__((address_space(3))) u32* LP;
    __builtin_amdgcn_global_load_lds((GP)g, (LP)l, 16, 0, 0);
}

// ---------------------------------------------------------------------------
// Pre-split pass: fp32 -> (hi bf16, lo bf16), once per element.
// seg 0..2: query/key/value; seg 3..6: Wq/Wk/Wv/Wo. Wq folded with QSCALE.
// ---------------------------------------------------------------------------
__global__ __launch_bounds__(256) void presplit(
    const float* __restrict__ x0, const float* __restrict__ x1,
    const float* __restrict__ x2, const float* __restrict__ wq,
    const float* __restrict__ wk, const float* __restrict__ wv,
    const float* __restrict__ wo,
    u16* __restrict__ xh, u16* __restrict__ xl,
    u16* __restrict__ wh, u16* __restrict__ wl)
{
    const int seg = blockIdx.y;
    const float* src;
    u16 *dh, *dl;
    int n4;
    float sc = 1.f;
    if (seg < 3) {
        src = (seg == 0) ? x0 : (seg == 1) ? x1 : x2;
        dh = xh + (size_t)seg * 4194304;
        dl = xl + (size_t)seg * 4194304;
        n4 = 1048576;
    } else {
        int s2 = seg - 3;
        src = (s2 == 0) ? wq : (s2 == 1) ? wk : (s2 == 2) ? wv : wo;
        dh = wh + (size_t)s2 * 1048576;
        dl = wl + (size_t)s2 * 1048576;
        n4 = 262144;
        if (s2 == 0) sc = QSCALE;
    }
    for (int i = blockIdx.x * 256 + threadIdx.x; i < n4; i += gridDim.x * 256) {
        float4 v = ((const float4*)src)[i];
        u16 h0, h1, h2, h3, l0, l1, l2, l3;
        split2(v.x * sc, h0, l0); split2(v.y * sc, h1, l1);
        split2(v.z * sc, h2, l2); split2(v.w * sc, h3, l3);
        u16x4 hv = {h0, h1, h2, h3}, lv = {l0, l1, l2, l3};
        *(u16x4*)(dh + (size_t)i * 4) = hv;
        *(u16x4*)(dl + (size_t)i * 4) = lv;
    }
}

// ---------------------------------------------------------------------------
// Split-bf16 MFMA GEMM (m97 structure) — unchanged (proven in round 3).
// ---------------------------------------------------------------------------
template<int VAR>
__global__ __launch_bounds__(256, 2) void gemm2(
    const u16* __restrict__ xh3, const u16* __restrict__ xl3,
    const u16* __restrict__ wh4, const u16* __restrict__ wl4,
    const float* bq, const float* bk, const float* bv,
    u16* qh, u16* ql, u16* kh, u16* kl, u16* vh, u16* vl,
    float* outf)
{
    __shared__ u16 Ah[128][32], Al[128][32], Bh[128][32], Bl[128][32];

    const int tid = threadIdx.x, lane = tid & 63, w = tid >> 6;
    const int lg = lane >> 4, lc = lane & 15;

    const int id = blockIdx.x + 8 * blockIdx.y;
    const int swz = (id & 7) * 32 + (id >> 3);
    const int c0 = (swz & 7) * 128, r0 = (swz >> 3) * 128;

    const u16 *ag, *alg, *bg, *blg;
    const float* bias;
    u16 *oh = nullptr, *ol = nullptr;
    float bsc = 1.f;
    int mode;
    if (VAR == 0) {
        const int z = blockIdx.z;
        ag  = xh3 + (size_t)z * 4194304;
        alg = xl3 + (size_t)z * 4194304;
        bg  = wh4 + (size_t)z * 1048576;
        blg = wl4 + (size_t)z * 1048576;
        if (z == 0)      { bias = bq; oh = qh; ol = ql; bsc = QSCALE; mode = 1; }
        else if (z == 1) { bias = bk; oh = kh; ol = kl; mode = 1; }
        else             { bias = bv; oh = vh; ol = vl; mode = 2; }
    } else {
        ag = xh3; alg = xl3; bg = wh4; blg = wl4; bias = bq; mode = 0;
    }

    const u16* gb = (w == 0) ? ag : (w == 1) ? alg : (w == 2) ? bg : blg;
    u16* lb = (w == 0) ? &Ah[0][0] : (w == 1) ? &Al[0][0] : (w == 2) ? &Bh[0][0] : &Bl[0][0];
    const int rbase = (w < 2) ? r0 : c0;
    const u16* gsrc0 = gb + (size_t)(rbase + (lane >> 2)) * DM + (lane & 3) * 8;

    const int wr = (w >> 1) * 64, wc = (w & 1) * 64;

    f32x4 acc[4][4];
#pragma unroll
    for (int i = 0; i < 4; ++i)
#pragma unroll
        for (int j = 0; j < 4; ++j) acc[i][j] = (f32x4)0.f;

    for (int ks = 0; ks < DM; ks += 32) {
        __syncthreads();
#pragma unroll
        for (int i = 0; i < 8; ++i)
            async16(gsrc0 + (size_t)i * 16 * DM + ks, lb + i * 512);
        __syncthreads();

        bf16x8 ah[4], al[4];
#pragma unroll
        for (int rt = 0; rt < 4; ++rt) {
            ah[rt] = *(const bf16x8*)&Ah[wr + rt * 16 + lc][lg * 8];
            al[rt] = *(const bf16x8*)&Al[wr + rt * 16 + lc][lg * 8];
        }
#pragma unroll
        for (int jt = 0; jt < 4; ++jt) {
            bf16x8 bh2 = *(const bf16x8*)&Bh[wc + jt * 16 + lc][lg * 8];
            bf16x8 bl2 = *(const bf16x8*)&Bl[wc + jt * 16 + lc][lg * 8];
#pragma unroll
            for (int rt = 0; rt < 4; ++rt) {
                acc[rt][jt] = MFMA(ah[rt], bh2, acc[rt][jt], 0, 0, 0);
                acc[rt][jt] = MFMA(ah[rt], bl2, acc[rt][jt], 0, 0, 0);
                acc[rt][jt] = MFMA(al[rt], bh2, acc[rt][jt], 0, 0, 0);
            }
        }
    }

#pragma unroll
    for (int rt = 0; rt < 4; ++rt)
#pragma unroll
        for (int jt = 0; jt < 4; ++jt)
#pragma unroll
            for (int r = 0; r < 4; ++r) {
                int row = r0 + wr + rt * 16 + lg * 4 + r;
                int col = c0 + wc + jt * 16 + lc;
                float v = acc[rt][jt][r] + bias[col] * bsc;
                if (mode == 0) {
                    outf[(size_t)row * DM + col] = v;
                } else if (mode == 1) {
                    int h = col >> 6, d = col & 63, n = row >> 11, s = row & 2047;
                    size_t idx = ((size_t)((h << 1) | n) * SEQ + s) * HD + d;
                    u16 hh, ll; split2(v, hh, ll);
                    oh[idx] = hh; ol[idx] = ll;
                } else {
                    int h = col >> 6, d = col & 63, n = row >> 11, s = row & 2047;
                    size_t idx = ((size_t)((h << 1) | n) * HD + d) * SEQ + s;
                    u16 hh, ll; split2(v, hh, ll);
                    oh[idx] = hh; ol[idx] = ll;
                }
            }
}

// ---------------------------------------------------------------------------
// Flash attention, swapped-operand (T12-style) split-bf16 MFMA.
// S^T = mfma(K, Q): rows=l (jt*16+lg*4+r), cols=q (rt*16+lc) -> softmax
//   reduce = 15 local fmax + 2 shfls; m,sum are per-lane scalars (q=lc).
// P^T stored to Pb as row-major P[q][l] (transpose free in the store
//   indexing), packed bf16 pairs via v_cvt_pk_bf16_f32, ds_write_b64.
// O^T = mfma(V^T, P^T): rows=d, cols=q=lc -> rescale shuffle-free.
// T13 defer-max (THR=8 in log2 units). exp2 direct (scale folded in Wq).
// XCD-chunked block swizzle: XCD x serves hn in [4x, 4x+4) (K/V L2 reuse).
// ---------------------------------------------------------------------------
__global__ __launch_bounds__(256, 2) void attn_k(
    const u16* __restrict__ qh, const u16* __restrict__ ql,
    const u16* __restrict__ kh, const u16* __restrict__ kl,
    const u16* __restrict__ vth, const u16* __restrict__ vtl,
    u16* __restrict__ yh, u16* __restrict__ yl)
{
    __shared__ u16 KsH[64][72], KsL[64][72], VsH[64][72], VsL[64][72];
    __shared__ u16 Pb[4][32][72];

    const int tid = threadIdx.x, lane = tid & 63, w = tid >> 6;
    const int lg = lane >> 4, lc = lane & 15;

    // bijective XCD-chunk swizzle over 512 blocks (512 % 8 == 0)
    const int id = blockIdx.x + 16 * blockIdx.y;
    const int widx = (id & 7) * 64 + (id >> 3);
    const int hn = widx >> 4;
    const int qb0 = (widx & 15) * 128;

    // Q fragments (hi/lo) — B-operand now; same per-lane load pattern
    bf16x8 qfh[2][2], qfl[2][2];
    const size_t qkbase = (size_t)hn * SEQ * HD;
#pragma unroll
    for (int rt = 0; rt < 2; ++rt)
#pragma unroll
        for (int kc = 0; kc < 2; ++kc) {
            size_t off = qkbase + (size_t)(qb0 + w * 32 + rt * 16 + lc) * HD + kc * 32 + lg * 8;
            qfh[rt][kc] = *(const bf16x8*)(qh + off);
            qfl[rt][kc] = *(const bf16x8*)(ql + off);
        }

    // O^T accumulator [rt][dt]: row = d = dt*16+lg*4+r, col = q = rt*16+lc
    f32x4 ot[2][4];
#pragma unroll
    for (int i = 0; i < 2; ++i)
#pragma unroll
        for (int j = 0; j < 4; ++j) ot[i][j] = (f32x4)0.f;
    float m_[2] = {-3e38f, -3e38f};
    float s_[2] = {0.f, 0.f};

    const size_t vbase = (size_t)hn * HD * SEQ;

    for (int kt = 0; kt < SEQ; kt += 64) {
        __syncthreads();
#pragma unroll
        for (int i = 0; i < 2; ++i) {
            int f = tid + 256 * i, row = f >> 3, kb = (f & 7) * 8;
            size_t ksrc = qkbase + (size_t)(kt + row) * HD + kb;
            *(bf16x8*)&KsH[row][kb] = *(const bf16x8*)(kh + ksrc);
            *(bf16x8*)&KsL[row][kb] = *(const bf16x8*)(kl + ksrc);
            size_t vsrc = vbase + (size_t)row * SEQ + kt + kb;   // row = d
            *(bf16x8*)&VsH[row][kb] = *(const bf16x8*)(vth + vsrc);
            *(bf16x8*)&VsL[row][kb] = *(const bf16x8*)(vtl + vsrc);
        }
        __syncthreads();

        // ---- S^T = K·Q^T (3-term split): st[rt][jt], row=l, col=q ----
        f32x4 st[2][4];
#pragma unroll
        for (int i = 0; i < 2; ++i)
#pragma unroll
            for (int j = 0; j < 4; ++j) st[i][j] = (f32x4)0.f;
#pragma unroll
        for (int jt = 0; jt < 4; ++jt)
#pragma unroll
            for (int kc = 0; kc < 2; ++kc) {
                bf16x8 kh8 = *(const bf16x8*)&KsH[jt * 16 + lc][kc * 32 + lg * 8];
                bf16x8 kl8 = *(const bf16x8*)&KsL[jt * 16 + lc][kc * 32 + lg * 8];
#pragma unroll
                for (int rt = 0; rt < 2; ++rt) {
                    st[rt][jt] = MFMA(kh8, qfh[rt][kc], st[rt][jt], 0, 0, 0);
                    st[rt][jt] = MFMA(kh8, qfl[rt][kc], st[rt][jt], 0, 0, 0);
                    st[rt][jt] = MFMA(kl8, qfh[rt][kc], st[rt][jt], 0, 0, 0);
                }
            }

        // ---- softmax (per q=lc; scores already in log2 units) ----
#pragma unroll
        for (int rt = 0; rt < 2; ++rt) {
            float t0 = fmaxf(fmaxf(st[rt][0][0], st[rt][0][1]),
                             fmaxf(st[rt][0][2], st[rt][0][3]));
            float t1 = fmaxf(fmaxf(st[rt][1][0], st[rt][1][1]),
                             fmaxf(st[rt][1][2], st[rt][1][3]));
            float t2 = fmaxf(fmaxf(st[rt][2][0], st[rt][2][1]),
                             fmaxf(st[rt][2][2], st[rt][2][3]));
            float t3 = fmaxf(fmaxf(st[rt][3][0], st[rt][3][1]),
                             fmaxf(st[rt][3][2], st[rt][3][3]));
            float t = fmaxf(fmaxf(t0, t1), fmaxf(t2, t3));
            t = fmaxf(t, __shfl_xor(t, 16));
            t = fmaxf(t, __shfl_xor(t, 32));
            // T13 defer-max: only rescale when the max grew past THR=8
            if (__any(t - m_[rt] > 8.0f)) {
                float mnew = fmaxf(m_[rt], t);
                float resc = exp2_fast(m_[rt] - mnew);
                m_[rt] = mnew;
                s_[rt] *= resc;
#pragma unroll
                for (int dt = 0; dt < 4; ++dt) {
                    ot[rt][dt][0] *= resc; ot[rt][dt][1] *= resc;
                    ot[rt][dt][2] *= resc; ot[rt][dt][3] *= resc;
                }
            }
            const float mm = m_[rt];
#pragma unroll
            for (int jt = 0; jt < 4; ++jt) {
                float p0 = exp2_fast(st[rt][jt][0] - mm);
                float p1 = exp2_fast(st[rt][jt][1] - mm);
                float p2 = exp2_fast(st[rt][jt][2] - mm);
                float p3 = exp2_fast(st[rt][jt][3] - mm);
                s_[rt] += (p0 + p1) + (p2 + p3);
                u32x2 pk = {cvt_pk_bf16(p0, p1), cvt_pk_bf16(p2, p3)};
                // transpose-free store: P[q = rt*16+lc][l = jt*16+lg*4 .. +3]
                *(u32x2*)&Pb[w][rt * 16 + lc][jt * 16 + lg * 4] = pk;
            }
        }

        // ---- O^T += V^T · P^T (v hi/lo, p plain bf16) ----
        bf16x8 pb[2][2];
#pragma unroll
        for (int rt = 0; rt < 2; ++rt)
#pragma unroll
            for (int jc = 0; jc < 2; ++jc)
                pb[rt][jc] = *(const bf16x8*)&Pb[w][rt * 16 + lc][jc * 32 + lg * 8];
#pragma unroll
        for (int dt = 0; dt < 4; ++dt)
#pragma unroll
            for (int jc = 0; jc < 2; ++jc) {
                bf16x8 vh8 = *(const bf16x8*)&VsH[dt * 16 + lc][jc * 32 + lg * 8];
                bf16x8 vl8 = *(const bf16x8*)&VsL[dt * 16 + lc][jc * 32 + lg * 8];
#pragma unroll
                for (int rt = 0; rt < 2; ++rt) {
                    ot[rt][dt] = MFMA(vh8, pb[rt][jc], ot[rt][dt], 0, 0, 0);
                    ot[rt][dt] = MFMA(vl8, pb[rt][jc], ot[rt][dt], 0, 0, 0);
                }
            }
    }

    // ---- epilogue: reduce sums over lg, normalize, write y (hi/lo) ----
    const int h = hn >> 1, n = hn & 1;
#pragma unroll
    for (int rt = 0; rt < 2; ++rt) {
        float v = s_[rt];
        v += __shfl_xor(v, 16);
        v += __shfl_xor(v, 32);
        s_[rt] = 1.f / v;
    }
#pragma unroll
    for (int rt = 0; rt < 2; ++rt) {
        const int srow = qb0 + w * 32 + rt * 16 + lc;
        size_t rowoff = (size_t)(n * SEQ + srow) * DM + h * HD;
#pragma unroll
        for (int dt = 0; dt < 4; ++dt) {
            u16x4 hv, lv;
#pragma unroll
            for (int r = 0; r < 4; ++r) {
                float y = ot[rt][dt][r] * s_[rt];
                u16 hh, ll; split2(y, hh, ll);
                hv[r] = hh; lv[r] = ll;
            }
            size_t idx = rowoff + dt * 16 + lg * 4;
            *(u16x4*)(yh + idx) = hv;
            *(u16x4*)(yl + idx) = lv;
        }
    }
}

// ---------------------------------------------------------------------------
extern "C" void kernel_launch(void* const* d_in, const int* in_sizes, int n_in,
                              void* d_out, int out_size, void* d_ws, size_t ws_size,
                              hipStream_t stream)
{
    const float* query = (const float*)d_in[0];
    const float* key_  = (const float*)d_in[1];
    const float* value = (const float*)d_in[2];
    const float* Wq = (const float*)d_in[3];
    const float* bq = (const float*)d_in[4];
    const float* Wk = (const float*)d_in[5];
    const float* bk = (const float*)d_in[6];
    const float* Wv = (const float*)d_in[7];
    const float* bv = (const float*)d_in[8];
    const float* Wo = (const float*)d_in[9];
    const float* bo = (const float*)d_in[10];
    float* out = (float*)d_out;

    // ws map (112 MiB):
    //   0MB  wh[4]   (8MB)     8MB  wl[4]   (8MB)
    //  16MB  qh ql kh kl vth vtl  (6 x 8MB = 48MB)
    //  64MB  xh[3]  (24MB)  -- reused after QKV: yh @64MB, yl @72MB
    //  88MB  xl[3]  (24MB)
    char* p = (char*)d_ws;
    u16* wh  = (u16*)(p);
    u16* wl  = (u16*)(p + 8388608ull);
    u16* qh  = (u16*)(p + 16777216ull);
    u16* ql  = (u16*)(p + 25165824ull);
    u16* kh  = (u16*)(p + 33554432ull);
    u16* kl  = (u16*)(p + 41943040ull);
    u16* vth = (u16*)(p + 50331648ull);
    u16* vtl = (u16*)(p + 58720256ull);
    u16* xh  = (u16*)(p + 67108864ull);
    u16* xl  = (u16*)(p + 92274688ull);
    u16* yh  = (u16*)(p + 67108864ull);
    u16* yl  = (u16*)(p + 75497472ull);

    presplit<<<dim3(256, 7), 256, 0, stream>>>(
        query, key_, value, Wq, Wk, Wv, Wo, xh, xl, wh, wl);

    gemm2<0><<<dim3(8, 32, 3), 256, 0, stream>>>(
        xh, xl, wh, wl, bq, bk, bv,
        qh, ql, kh, kl, vth, vtl, nullptr);

    attn_k<<<dim3(16, 32), 256, 0, stream>>>(qh, ql, kh, kl, vth, vtl, yh, yl);

    gemm2<1><<<dim3(8, 32, 1), 256, 0, stream>>>(
        yh, yl, wh + 3145728ull, wl + 3145728ull, bo, nullptr, nullptr,
        nullptr, nullptr, nullptr, nullptr, nullptr, nullptr, out);
}

// Round 6
// 332.318 us; speedup vs baseline: 8.5060x; 1.1077x over previous
//
#include <hip/hip_runtime.h>
#include <hip/hip_bf16.h>

// N=2 batch, S=2048 seq, M=1024 d_model, H=16 heads, D=64 head dim
#define NB 2
#define SEQ 2048
#define DM 1024
#define NH 16
#define HD 64

typedef unsigned short u16;
typedef unsigned int u32;
typedef __attribute__((ext_vector_type(8))) short bf16x8;
typedef __attribute__((ext_vector_type(4))) float f32x4;
typedef __attribute__((ext_vector_type(4))) unsigned short u16x4;
typedef __attribute__((ext_vector_type(2))) unsigned int u32x2;

#define MFMA __builtin_amdgcn_mfma_f32_16x16x32_bf16

// log2(e) * 0.125  (attention scale folded with exp2 conversion)
#define QSCALE 0.18033688011112042f

__device__ __forceinline__ u16 bf16_rne(float x) {
    unsigned int u = __float_as_uint(x);
    return (u16)((u + 0x7FFFu + ((u >> 16) & 1u)) >> 16);
}
__device__ __forceinline__ float bf16f(u16 h) {
    return __uint_as_float(((unsigned int)h) << 16);
}
__device__ __forceinline__ void split2(float x, u16& h, u16& l) {
    h = bf16_rne(x);
    l = bf16_rne(x - bf16f(h));
}
// packed 2xf32 -> 2xbf16 (RNE), one instruction
__device__ __forceinline__ u32 cvt_pk_bf16(float lo, float hi) {
    u32 r;
    asm("v_cvt_pk_bf16_f32 %0, %1, %2" : "=v"(r) : "v"(lo), "v"(hi));
    return r;
}
// 2^x on the transcendental pipe
__device__ __forceinline__ float exp2_fast(float x) {
#if __has_builtin(__builtin_amdgcn_exp2f)
    return __builtin_amdgcn_exp2f(x);
#else
    float r;
    asm("v_exp_f32 %0, %1" : "=v"(r) : "v"(x));
    return r;
#endif
}

// async global->LDS, 16B per lane. LDS dest = wave-uniform base + lane*16.
__device__ __forceinline__ void async16(const u16* g, u16* l) {
    typedef const __attribute__((address_space(1))) u32* GP;
    typedef __attribute__((address_space(3))) u32* LP;
    __builtin_amdgcn_global_load_lds((GP)g, (LP)l, 16, 0, 0);
}

// ---------------------------------------------------------------------------
// Pre-split pass: fp32 -> (hi bf16, lo bf16), once per element.
// seg 0..2: query/key/value; seg 3..6: Wq/Wk/Wv/Wo. Wq folded with QSCALE.
// ---------------------------------------------------------------------------
__global__ __launch_bounds__(256) void presplit(
    const float* __restrict__ x0, const float* __restrict__ x1,
    const float* __restrict__ x2, const float* __restrict__ wq,
    const float* __restrict__ wk, const float* __restrict__ wv,
    const float* __restrict__ wo,
    u16* __restrict__ xh, u16* __restrict__ xl,
    u16* __restrict__ wh, u16* __restrict__ wl)
{
    const int seg = blockIdx.y;
    const float* src;
    u16 *dh, *dl;
    int n4;
    float sc = 1.f;
    if (seg < 3) {
        src = (seg == 0) ? x0 : (seg == 1) ? x1 : x2;
        dh = xh + (size_t)seg * 4194304;
        dl = xl + (size_t)seg * 4194304;
        n4 = 1048576;
    } else {
        int s2 = seg - 3;
        src = (s2 == 0) ? wq : (s2 == 1) ? wk : (s2 == 2) ? wv : wo;
        dh = wh + (size_t)s2 * 1048576;
        dl = wl + (size_t)s2 * 1048576;
        n4 = 262144;
        if (s2 == 0) sc = QSCALE;
    }
    for (int i = blockIdx.x * 256 + threadIdx.x; i < n4; i += gridDim.x * 256) {
        float4 v = ((const float4*)src)[i];
        u16 h0, h1, h2, h3, l0, l1, l2, l3;
        split2(v.x * sc, h0, l0); split2(v.y * sc, h1, l1);
        split2(v.z * sc, h2, l2); split2(v.w * sc, h3, l3);
        u16x4 hv = {h0, h1, h2, h3}, lv = {l0, l1, l2, l3};
        *(u16x4*)(dh + (size_t)i * 4) = hv;
        *(u16x4*)(dl + (size_t)i * 4) = lv;
    }
}

// ---------------------------------------------------------------------------
// Split-bf16 MFMA GEMM (m97 structure).
// VAR 0 (QKV fused over z): z=0 Q -> hi/lo scatter [hn][s][64] (bias*QSCALE);
//   z=1 K -> hi-ONLY scatter [hn][s][64] (attn uses plain-bf16 K);
//   z=2 V -> hi-ONLY scatter transposed [hn][64][s].
// VAR 1: final projection, fp32 out + bo.
// ---------------------------------------------------------------------------
template<int VAR>
__global__ __launch_bounds__(256, 2) void gemm2(
    const u16* __restrict__ xh3, const u16* __restrict__ xl3,
    const u16* __restrict__ wh4, const u16* __restrict__ wl4,
    const float* bq, const float* bk, const float* bv,
    u16* qh, u16* ql, u16* kh, u16* kl, u16* vh, u16* vl,
    float* outf)
{
    __shared__ u16 Ah[128][32], Al[128][32], Bh[128][32], Bl[128][32];

    const int tid = threadIdx.x, lane = tid & 63, w = tid >> 6;
    const int lg = lane >> 4, lc = lane & 15;

    const int id = blockIdx.x + 8 * blockIdx.y;
    const int swz = (id & 7) * 32 + (id >> 3);
    const int c0 = (swz & 7) * 128, r0 = (swz >> 3) * 128;

    const u16 *ag, *alg, *bg, *blg;
    const float* bias;
    u16 *oh = nullptr, *ol = nullptr;
    float bsc = 1.f;
    int mode;
    if (VAR == 0) {
        const int z = blockIdx.z;
        ag  = xh3 + (size_t)z * 4194304;
        alg = xl3 + (size_t)z * 4194304;
        bg  = wh4 + (size_t)z * 1048576;
        blg = wl4 + (size_t)z * 1048576;
        if (z == 0)      { bias = bq; oh = qh; ol = ql; bsc = QSCALE; mode = 1; }
        else if (z == 1) { bias = bk; oh = kh; mode = 2; }
        else             { bias = bv; oh = vh; mode = 3; }
    } else {
        ag = xh3; alg = xl3; bg = wh4; blg = wl4; bias = bq; mode = 0;
    }

    const u16* gb = (w == 0) ? ag : (w == 1) ? alg : (w == 2) ? bg : blg;
    u16* lb = (w == 0) ? &Ah[0][0] : (w == 1) ? &Al[0][0] : (w == 2) ? &Bh[0][0] : &Bl[0][0];
    const int rbase = (w < 2) ? r0 : c0;
    const u16* gsrc0 = gb + (size_t)(rbase + (lane >> 2)) * DM + (lane & 3) * 8;

    const int wr = (w >> 1) * 64, wc = (w & 1) * 64;

    f32x4 acc[4][4];
#pragma unroll
    for (int i = 0; i < 4; ++i)
#pragma unroll
        for (int j = 0; j < 4; ++j) acc[i][j] = (f32x4)0.f;

    for (int ks = 0; ks < DM; ks += 32) {
        __syncthreads();
#pragma unroll
        for (int i = 0; i < 8; ++i)
            async16(gsrc0 + (size_t)i * 16 * DM + ks, lb + i * 512);
        __syncthreads();

        bf16x8 ah[4], al[4];
#pragma unroll
        for (int rt = 0; rt < 4; ++rt) {
            ah[rt] = *(const bf16x8*)&Ah[wr + rt * 16 + lc][lg * 8];
            al[rt] = *(const bf16x8*)&Al[wr + rt * 16 + lc][lg * 8];
        }
#pragma unroll
        for (int jt = 0; jt < 4; ++jt) {
            bf16x8 bh2 = *(const bf16x8*)&Bh[wc + jt * 16 + lc][lg * 8];
            bf16x8 bl2 = *(const bf16x8*)&Bl[wc + jt * 16 + lc][lg * 8];
#pragma unroll
            for (int rt = 0; rt < 4; ++rt) {
                acc[rt][jt] = MFMA(ah[rt], bh2, acc[rt][jt], 0, 0, 0);
                acc[rt][jt] = MFMA(ah[rt], bl2, acc[rt][jt], 0, 0, 0);
                acc[rt][jt] = MFMA(al[rt], bh2, acc[rt][jt], 0, 0, 0);
            }
        }
    }

#pragma unroll
    for (int rt = 0; rt < 4; ++rt)
#pragma unroll
        for (int jt = 0; jt < 4; ++jt)
#pragma unroll
            for (int r = 0; r < 4; ++r) {
                int row = r0 + wr + rt * 16 + lg * 4 + r;
                int col = c0 + wc + jt * 16 + lc;
                float v = acc[rt][jt][r] + bias[col] * bsc;
                if (mode == 0) {
                    outf[(size_t)row * DM + col] = v;
                } else {
                    int h = col >> 6, d = col & 63, n = row >> 11, s = row & 2047;
                    if (mode == 1) {
                        size_t idx = ((size_t)((h << 1) | n) * SEQ + s) * HD + d;
                        u16 hh, ll; split2(v, hh, ll);
                        oh[idx] = hh; ol[idx] = ll;
                    } else if (mode == 2) {
                        size_t idx = ((size_t)((h << 1) | n) * SEQ + s) * HD + d;
                        oh[idx] = bf16_rne(v);
                    } else {
                        size_t idx = ((size_t)((h << 1) | n) * HD + d) * SEQ + s;
                        oh[idx] = bf16_rne(v);
                    }
                }
            }
}

// ---------------------------------------------------------------------------
// Flash attention, swapped-operand split-bf16 MFMA, plain-bf16 K/V.
// S^T = mfma(K, Q): 2-term (q hi/lo, k plain). P^T packed bf16 via LDS
// bounce (round-5-verified indexing). O^T = mfma(V^T, P^T): 1-term.
// LDS 36.9 KB -> 4 blocks/CU (occupancy 2x vs round 5). T5 setprio
// around both MFMA clusters. T13 defer-max. XCD-chunked swizzle.
// ---------------------------------------------------------------------------
__global__ __launch_bounds__(256, 4) void attn_k(
    const u16* __restrict__ qh, const u16* __restrict__ ql,
    const u16* __restrict__ kh, const u16* __restrict__ vth,
    u16* __restrict__ yh, u16* __restrict__ yl)
{
    __shared__ u16 Ks[64][72], Vs[64][72];
    __shared__ u16 Pb[4][32][72];

    const int tid = threadIdx.x, lane = tid & 63, w = tid >> 6;
    const int lg = lane >> 4, lc = lane & 15;

    // bijective XCD-chunk swizzle over 512 blocks (512 % 8 == 0)
    const int id = blockIdx.x + 16 * blockIdx.y;
    const int widx = (id & 7) * 64 + (id >> 3);
    const int hn = widx >> 4;
    const int qb0 = (widx & 15) * 128;

    // Q fragments (hi/lo) — B-operand; resident in registers
    bf16x8 qfh[2][2], qfl[2][2];
    const size_t qkbase = (size_t)hn * SEQ * HD;
#pragma unroll
    for (int rt = 0; rt < 2; ++rt)
#pragma unroll
        for (int kc = 0; kc < 2; ++kc) {
            size_t off = qkbase + (size_t)(qb0 + w * 32 + rt * 16 + lc) * HD + kc * 32 + lg * 8;
            qfh[rt][kc] = *(const bf16x8*)(qh + off);
            qfl[rt][kc] = *(const bf16x8*)(ql + off);
        }

    // O^T accumulator [rt][dt]: row = d = dt*16+lg*4+r, col = q = rt*16+lc
    f32x4 ot[2][4];
#pragma unroll
    for (int i = 0; i < 2; ++i)
#pragma unroll
        for (int j = 0; j < 4; ++j) ot[i][j] = (f32x4)0.f;
    float m_[2] = {-3e38f, -3e38f};
    float s_[2] = {0.f, 0.f};

    const size_t vbase = (size_t)hn * HD * SEQ;

    for (int kt = 0; kt < SEQ; kt += 64) {
        __syncthreads();
#pragma unroll
        for (int i = 0; i < 2; ++i) {
            int f = tid + 256 * i, row = f >> 3, kb = (f & 7) * 8;
            size_t ksrc = qkbase + (size_t)(kt + row) * HD + kb;
            *(bf16x8*)&Ks[row][kb] = *(const bf16x8*)(kh + ksrc);
            size_t vsrc = vbase + (size_t)row * SEQ + kt + kb;   // row = d
            *(bf16x8*)&Vs[row][kb] = *(const bf16x8*)(vth + vsrc);
        }
        __syncthreads();

        // ---- S^T = K·Q^T (2-term: k plain, q hi/lo) ----
        f32x4 st[2][4];
#pragma unroll
        for (int i = 0; i < 2; ++i)
#pragma unroll
            for (int j = 0; j < 4; ++j) st[i][j] = (f32x4)0.f;
        __builtin_amdgcn_s_setprio(1);
#pragma unroll
        for (int jt = 0; jt < 4; ++jt)
#pragma unroll
            for (int kc = 0; kc < 2; ++kc) {
                bf16x8 k8 = *(const bf16x8*)&Ks[jt * 16 + lc][kc * 32 + lg * 8];
#pragma unroll
                for (int rt = 0; rt < 2; ++rt) {
                    st[rt][jt] = MFMA(k8, qfh[rt][kc], st[rt][jt], 0, 0, 0);
                    st[rt][jt] = MFMA(k8, qfl[rt][kc], st[rt][jt], 0, 0, 0);
                }
            }
        __builtin_amdgcn_s_setprio(0);

        // ---- softmax (per q=lc; scores already in log2 units) ----
#pragma unroll
        for (int rt = 0; rt < 2; ++rt) {
            float t0 = fmaxf(fmaxf(st[rt][0][0], st[rt][0][1]),
                             fmaxf(st[rt][0][2], st[rt][0][3]));
            float t1 = fmaxf(fmaxf(st[rt][1][0], st[rt][1][1]),
                             fmaxf(st[rt][1][2], st[rt][1][3]));
            float t2 = fmaxf(fmaxf(st[rt][2][0], st[rt][2][1]),
                             fmaxf(st[rt][2][2], st[rt][2][3]));
            float t3 = fmaxf(fmaxf(st[rt][3][0], st[rt][3][1]),
                             fmaxf(st[rt][3][2], st[rt][3][3]));
            float t = fmaxf(fmaxf(t0, t1), fmaxf(t2, t3));
            t = fmaxf(t, __shfl_xor(t, 16));
            t = fmaxf(t, __shfl_xor(t, 32));
            // T13 defer-max: only rescale when the max grew past THR=8
            if (__any(t - m_[rt] > 8.0f)) {
                float mnew = fmaxf(m_[rt], t);
                float resc = exp2_fast(m_[rt] - mnew);
                m_[rt] = mnew;
                s_[rt] *= resc;
#pragma unroll
                for (int dt = 0; dt < 4; ++dt) {
                    ot[rt][dt][0] *= resc; ot[rt][dt][1] *= resc;
                    ot[rt][dt][2] *= resc; ot[rt][dt][3] *= resc;
                }
            }
            const float mm = m_[rt];
#pragma unroll
            for (int jt = 0; jt < 4; ++jt) {
                float p0 = exp2_fast(st[rt][jt][0] - mm);
                float p1 = exp2_fast(st[rt][jt][1] - mm);
                float p2 = exp2_fast(st[rt][jt][2] - mm);
                float p3 = exp2_fast(st[rt][jt][3] - mm);
                s_[rt] += (p0 + p1) + (p2 + p3);
                u32x2 pk = {cvt_pk_bf16(p0, p1), cvt_pk_bf16(p2, p3)};
                // transpose-free store: P[q = rt*16+lc][l = jt*16+lg*4 .. +3]
                *(u32x2*)&Pb[w][rt * 16 + lc][jt * 16 + lg * 4] = pk;
            }
        }

        // ---- O^T += V^T · P^T (v plain, p plain bf16) ----
        bf16x8 pb[2][2];
#pragma unroll
        for (int rt = 0; rt < 2; ++rt)
#pragma unroll
            for (int jc = 0; jc < 2; ++jc)
                pb[rt][jc] = *(const bf16x8*)&Pb[w][rt * 16 + lc][jc * 32 + lg * 8];
        __builtin_amdgcn_s_setprio(1);
#pragma unroll
        for (int dt = 0; dt < 4; ++dt)
#pragma unroll
            for (int jc = 0; jc < 2; ++jc) {
                bf16x8 v8 = *(const bf16x8*)&Vs[dt * 16 + lc][jc * 32 + lg * 8];
#pragma unroll
                for (int rt = 0; rt < 2; ++rt)
                    ot[rt][dt] = MFMA(v8, pb[rt][jc], ot[rt][dt], 0, 0, 0);
            }
        __builtin_amdgcn_s_setprio(0);
    }

    // ---- epilogue: reduce sums over lg, normalize, write y (hi/lo) ----
    const int h = hn >> 1, n = hn & 1;
#pragma unroll
    for (int rt = 0; rt < 2; ++rt) {
        float v = s_[rt];
        v += __shfl_xor(v, 16);
        v += __shfl_xor(v, 32);
        s_[rt] = 1.f / v;
    }
#pragma unroll
    for (int rt = 0; rt < 2; ++rt) {
        const int srow = qb0 + w * 32 + rt * 16 + lc;
        size_t rowoff = (size_t)(n * SEQ + srow) * DM + h * HD;
#pragma unroll
        for (int dt = 0; dt < 4; ++dt) {
            u16x4 hv, lv;
#pragma unroll
            for (int r = 0; r < 4; ++r) {
                float y = ot[rt][dt][r] * s_[rt];
                u16 hh, ll; split2(y, hh, ll);
                hv[r] = hh; lv[r] = ll;
            }
            size_t idx = rowoff + dt * 16 + lg * 4;
            *(u16x4*)(yh + idx) = hv;
            *(u16x4*)(yl + idx) = lv;
        }
    }
}

// ---------------------------------------------------------------------------
extern "C" void kernel_launch(void* const* d_in, const int* in_sizes, int n_in,
                              void* d_out, int out_size, void* d_ws, size_t ws_size,
                              hipStream_t stream)
{
    const float* query = (const float*)d_in[0];
    const float* key_  = (const float*)d_in[1];
    const float* value = (const float*)d_in[2];
    const float* Wq = (const float*)d_in[3];
    const float* bq = (const float*)d_in[4];
    const float* Wk = (const float*)d_in[5];
    const float* bk = (const float*)d_in[6];
    const float* Wv = (const float*)d_in[7];
    const float* bv = (const float*)d_in[8];
    const float* Wo = (const float*)d_in[9];
    const float* bo = (const float*)d_in[10];
    float* out = (float*)d_out;

    // ws map (112 MiB):
    //   0MB  wh[4]   (8MB)     8MB  wl[4]   (8MB)
    //  16MB  qh ql kh (kl unused) vth (vtl unused)  (6 x 8MB = 48MB)
    //  64MB  xh[3]  (24MB)  -- reused after QKV: yh @64MB, yl @72MB
    //  88MB  xl[3]  (24MB)
    char* p = (char*)d_ws;
    u16* wh  = (u16*)(p);
    u16* wl  = (u16*)(p + 8388608ull);
    u16* qh  = (u16*)(p + 16777216ull);
    u16* ql  = (u16*)(p + 25165824ull);
    u16* kh  = (u16*)(p + 33554432ull);
    u16* kl  = (u16*)(p + 41943040ull);
    u16* vth = (u16*)(p + 50331648ull);
    u16* vtl = (u16*)(p + 58720256ull);
    u16* xh  = (u16*)(p + 67108864ull);
    u16* xl  = (u16*)(p + 92274688ull);
    u16* yh  = (u16*)(p + 67108864ull);
    u16* yl  = (u16*)(p + 75497472ull);

    presplit<<<dim3(256, 7), 256, 0, stream>>>(
        query, key_, value, Wq, Wk, Wv, Wo, xh, xl, wh, wl);

    gemm2<0><<<dim3(8, 32, 3), 256, 0, stream>>>(
        xh, xl, wh, wl, bq, bk, bv,
        qh, ql, kh, kl, vth, vtl, nullptr);

    attn_k<<<dim3(16, 32), 256, 0, stream>>>(qh, ql, kh, vth, yh, yl);

    gemm2<1><<<dim3(8, 32, 1), 256, 0, stream>>>(
        yh, yl, wh + 3145728ull, wl + 3145728ull, bo, nullptr, nullptr,
        nullptr, nullptr, nullptr, nullptr, nullptr, nullptr, out);
}

// Round 7
// 280.605 us; speedup vs baseline: 10.0736x; 1.1843x over previous
//
#include <hip/hip_runtime.h>
#include <hip/hip_bf16.h>

// N=2 batch, S=2048 seq, M=1024 d_model, H=16 heads, D=64 head dim
#define NB 2
#define SEQ 2048
#define DM 1024
#define NH 16
#define HD 64

typedef unsigned short u16;
typedef unsigned int u32;
typedef __attribute__((ext_vector_type(8))) short bf16x8;
typedef __attribute__((ext_vector_type(4))) float f32x4;
typedef __attribute__((ext_vector_type(4))) unsigned short u16x4;
typedef __attribute__((ext_vector_type(2))) unsigned int u32x2;

#define MFMA __builtin_amdgcn_mfma_f32_16x16x32_bf16

// log2(e) * 0.125  (attention scale folded with exp2 conversion)
#define QSCALE 0.18033688011112042f

__device__ __forceinline__ u16 bf16_rne(float x) {
    unsigned int u = __float_as_uint(x);
    return (u16)((u + 0x7FFFu + ((u >> 16) & 1u)) >> 16);
}
__device__ __forceinline__ float bf16f(u16 h) {
    return __uint_as_float(((unsigned int)h) << 16);
}
__device__ __forceinline__ void split2(float x, u16& h, u16& l) {
    h = bf16_rne(x);
    l = bf16_rne(x - bf16f(h));
}
// packed 2xf32 -> 2xbf16 (RNE), one instruction
__device__ __forceinline__ u32 cvt_pk_bf16(float lo, float hi) {
    u32 r;
    asm("v_cvt_pk_bf16_f32 %0, %1, %2" : "=v"(r) : "v"(lo), "v"(hi));
    return r;
}
// 2^x on the transcendental pipe
__device__ __forceinline__ float exp2_fast(float x) {
#if __has_builtin(__builtin_amdgcn_exp2f)
    return __builtin_amdgcn_exp2f(x);
#else
    float r;
    asm("v_exp_f32 %0, %1" : "=v"(r) : "v"(x));
    return r;
#endif
}

// async global->LDS, 16B per lane. LDS dest = wave-uniform base + lane*16.
__device__ __forceinline__ void async16(const u16* g, u16* l) {
    typedef const __attribute__((address_space(1))) u32* GP;
    typedef __attribute__((address_space(3))) u32* LP;
    __builtin_amdgcn_global_load_lds((GP)g, (LP)l, 16, 0, 0);
}

// ---------------------------------------------------------------------------
// Pre-split pass.
// seg 0..2: query/key/value -> HI ONLY (QKV gemm is 1-term now).
// seg 3..5: Wq/Wk/Wv -> HI ONLY (Wq folded with QSCALE).
// seg 6: Wo -> hi+lo (projection stays 3-term).
// ---------------------------------------------------------------------------
__global__ __launch_bounds__(256) void presplit(
    const float* __restrict__ x0, const float* __restrict__ x1,
    const float* __restrict__ x2, const float* __restrict__ wq,
    const float* __restrict__ wk, const float* __restrict__ wv,
    const float* __restrict__ wo,
    u16* __restrict__ xh, u16* __restrict__ wh, u16* __restrict__ wl)
{
    const int seg = blockIdx.y;
    const float* src;
    u16* dh;
    u16* dl = nullptr;
    int n4;
    float sc = 1.f;
    if (seg < 3) {
        src = (seg == 0) ? x0 : (seg == 1) ? x1 : x2;
        dh = xh + (size_t)seg * 4194304;
        n4 = 1048576;
    } else {
        int s2 = seg - 3;
        src = (s2 == 0) ? wq : (s2 == 1) ? wk : (s2 == 2) ? wv : wo;
        dh = wh + (size_t)s2 * 1048576;
        if (s2 == 3) dl = wl + (size_t)s2 * 1048576;   // Wo lo
        n4 = 262144;
        if (s2 == 0) sc = QSCALE;
    }
    for (int i = blockIdx.x * 256 + threadIdx.x; i < n4; i += gridDim.x * 256) {
        float4 v = ((const float4*)src)[i];
        v.x *= sc; v.y *= sc; v.z *= sc; v.w *= sc;
        u16 h0 = bf16_rne(v.x), h1 = bf16_rne(v.y);
        u16 h2 = bf16_rne(v.z), h3 = bf16_rne(v.w);
        u16x4 hv = {h0, h1, h2, h3};
        *(u16x4*)(dh + (size_t)i * 4) = hv;
        if (dl) {
            u16x4 lv = {bf16_rne(v.x - bf16f(h0)), bf16_rne(v.y - bf16f(h1)),
                        bf16_rne(v.z - bf16f(h2)), bf16_rne(v.w - bf16f(h3))};
            *(u16x4*)(dl + (size_t)i * 4) = lv;
        }
    }
}

// ---------------------------------------------------------------------------
// QKV GEMM, plain bf16 (1-term), BK=64 via four [128][32] arrays (A0,A1 =
// X cols ks/ks+32; B0,B1 = W cols ks/ks+32). Wave w stages array w with
// global_load_lds width-16 (proven staging pattern, half the barriers).
// z=0 Q -> hi/lo scatter [hn][s][64]; z=1 K -> bf16 [hn][s][64];
// z=2 V -> bf16 transposed [hn][64][s]. XCD swizzle as proven.
// ---------------------------------------------------------------------------
__global__ __launch_bounds__(256, 4) void gemm_qkv(
    const u16* __restrict__ xh3, const u16* __restrict__ wh3,
    const float* __restrict__ bq, const float* __restrict__ bk,
    const float* __restrict__ bv,
    u16* qh, u16* ql, u16* kh, u16* vth)
{
    __shared__ u16 A0[128][32], A1[128][32], B0[128][32], B1[128][32];

    const int tid = threadIdx.x, lane = tid & 63, w = tid >> 6;
    const int lg = lane >> 4, lc = lane & 15;

    const int id = blockIdx.x + 8 * blockIdx.y;
    const int swz = (id & 7) * 32 + (id >> 3);
    const int c0 = (swz & 7) * 128, r0 = (swz >> 3) * 128;

    const int z = blockIdx.z;
    const u16* ag = xh3 + (size_t)z * 4194304;
    const u16* bg = wh3 + (size_t)z * 1048576;
    const float* bias = (z == 0) ? bq : (z == 1) ? bk : bv;

    // wave w stages array w: w0->A0, w1->A1, w2->B0, w3->B1
    const u16* gb = (w < 2) ? ag : bg;
    u16* lb = (w == 0) ? &A0[0][0] : (w == 1) ? &A1[0][0]
            : (w == 2) ? &B0[0][0] : &B1[0][0];
    const int rbase = (w < 2) ? r0 : c0;
    const int colofs = (w & 1) * 32;
    const u16* gsrc0 = gb + (size_t)(rbase + (lane >> 2)) * DM + colofs + (lane & 3) * 8;

    const int wr = (w >> 1) * 64, wc = (w & 1) * 64;

    f32x4 acc[4][4];
#pragma unroll
    for (int i = 0; i < 4; ++i)
#pragma unroll
        for (int j = 0; j < 4; ++j) acc[i][j] = (f32x4)0.f;

    for (int ks = 0; ks < DM; ks += 64) {
        __syncthreads();
#pragma unroll
        for (int i = 0; i < 8; ++i)
            async16(gsrc0 + (size_t)i * 16 * DM + ks, lb + i * 512);
        __syncthreads();

#pragma unroll
        for (int kk = 0; kk < 2; ++kk) {
            const u16(*Ak)[32] = kk ? A1 : A0;
            const u16(*Bk)[32] = kk ? B1 : B0;
            bf16x8 ah[4], bh[4];
#pragma unroll
            for (int rt = 0; rt < 4; ++rt)
                ah[rt] = *(const bf16x8*)&Ak[wr + rt * 16 + lc][lg * 8];
#pragma unroll
            for (int jt = 0; jt < 4; ++jt)
                bh[jt] = *(const bf16x8*)&Bk[wc + jt * 16 + lc][lg * 8];
#pragma unroll
            for (int jt = 0; jt < 4; ++jt)
#pragma unroll
                for (int rt = 0; rt < 4; ++rt)
                    acc[rt][jt] = MFMA(ah[rt], bh[jt], acc[rt][jt], 0, 0, 0);
        }
    }

#pragma unroll
    for (int rt = 0; rt < 4; ++rt)
#pragma unroll
        for (int jt = 0; jt < 4; ++jt)
#pragma unroll
            for (int r = 0; r < 4; ++r) {
                int row = r0 + wr + rt * 16 + lg * 4 + r;
                int col = c0 + wc + jt * 16 + lc;
                int h = col >> 6, d = col & 63, n = row >> 11, s = row & 2047;
                if (z == 0) {
                    float v = acc[rt][jt][r] + bias[col] * QSCALE;
                    size_t idx = ((size_t)((h << 1) | n) * SEQ + s) * HD + d;
                    u16 hh, ll; split2(v, hh, ll);
                    qh[idx] = hh; ql[idx] = ll;
                } else if (z == 1) {
                    float v = acc[rt][jt][r] + bias[col];
                    size_t idx = ((size_t)((h << 1) | n) * SEQ + s) * HD + d;
                    kh[idx] = bf16_rne(v);
                } else {
                    float v = acc[rt][jt][r] + bias[col];
                    size_t idx = ((size_t)((h << 1) | n) * HD + d) * SEQ + s;
                    vth[idx] = bf16_rne(v);
                }
            }
}

// ---------------------------------------------------------------------------
// Final projection GEMM, 3-term split (output-facing; proven round-3 path).
// X = yh/yl bf16 pairs; W = Wo hi/lo; out fp32 + bo.
// ---------------------------------------------------------------------------
__global__ __launch_bounds__(256, 2) void gemm_proj(
    const u16* __restrict__ yh, const u16* __restrict__ yl,
    const u16* __restrict__ woh, const u16* __restrict__ wol,
    const float* __restrict__ bo, float* __restrict__ outf)
{
    __shared__ u16 Ah[128][32], Al[128][32], Bh[128][32], Bl[128][32];

    const int tid = threadIdx.x, lane = tid & 63, w = tid >> 6;
    const int lg = lane >> 4, lc = lane & 15;

    const int id = blockIdx.x + 8 * blockIdx.y;
    const int swz = (id & 7) * 32 + (id >> 3);
    const int c0 = (swz & 7) * 128, r0 = (swz >> 3) * 128;

    const u16* gb = (w == 0) ? yh : (w == 1) ? yl : (w == 2) ? woh : wol;
    u16* lb = (w == 0) ? &Ah[0][0] : (w == 1) ? &Al[0][0] : (w == 2) ? &Bh[0][0] : &Bl[0][0];
    const int rbase = (w < 2) ? r0 : c0;
    const u16* gsrc0 = gb + (size_t)(rbase + (lane >> 2)) * DM + (lane & 3) * 8;

    const int wr = (w >> 1) * 64, wc = (w & 1) * 64;

    f32x4 acc[4][4];
#pragma unroll
    for (int i = 0; i < 4; ++i)
#pragma unroll
        for (int j = 0; j < 4; ++j) acc[i][j] = (f32x4)0.f;

    for (int ks = 0; ks < DM; ks += 32) {
        __syncthreads();
#pragma unroll
        for (int i = 0; i < 8; ++i)
            async16(gsrc0 + (size_t)i * 16 * DM + ks, lb + i * 512);
        __syncthreads();

        bf16x8 ah[4], al[4];
#pragma unroll
        for (int rt = 0; rt < 4; ++rt) {
            ah[rt] = *(const bf16x8*)&Ah[wr + rt * 16 + lc][lg * 8];
            al[rt] = *(const bf16x8*)&Al[wr + rt * 16 + lc][lg * 8];
        }
#pragma unroll
        for (int jt = 0; jt < 4; ++jt) {
            bf16x8 bh2 = *(const bf16x8*)&Bh[wc + jt * 16 + lc][lg * 8];
            bf16x8 bl2 = *(const bf16x8*)&Bl[wc + jt * 16 + lc][lg * 8];
#pragma unroll
            for (int rt = 0; rt < 4; ++rt) {
                acc[rt][jt] = MFMA(ah[rt], bh2, acc[rt][jt], 0, 0, 0);
                acc[rt][jt] = MFMA(ah[rt], bl2, acc[rt][jt], 0, 0, 0);
                acc[rt][jt] = MFMA(al[rt], bh2, acc[rt][jt], 0, 0, 0);
            }
        }
    }

#pragma unroll
    for (int rt = 0; rt < 4; ++rt)
#pragma unroll
        for (int jt = 0; jt < 4; ++jt)
#pragma unroll
            for (int r = 0; r < 4; ++r) {
                int row = r0 + wr + rt * 16 + lg * 4 + r;
                int col = c0 + wc + jt * 16 + lc;
                outf[(size_t)row * DM + col] = acc[rt][jt][r] + bo[col];
            }
}

// ---------------------------------------------------------------------------
// Flash attention (unchanged from round 6 — proven, next round's target).
// ---------------------------------------------------------------------------
__global__ __launch_bounds__(256, 4) void attn_k(
    const u16* __restrict__ qh, const u16* __restrict__ ql,
    const u16* __restrict__ kh, const u16* __restrict__ vth,
    u16* __restrict__ yh, u16* __restrict__ yl)
{
    __shared__ u16 Ks[64][72], Vs[64][72];
    __shared__ u16 Pb[4][32][72];

    const int tid = threadIdx.x, lane = tid & 63, w = tid >> 6;
    const int lg = lane >> 4, lc = lane & 15;

    const int id = blockIdx.x + 16 * blockIdx.y;
    const int widx = (id & 7) * 64 + (id >> 3);
    const int hn = widx >> 4;
    const int qb0 = (widx & 15) * 128;

    bf16x8 qfh[2][2], qfl[2][2];
    const size_t qkbase = (size_t)hn * SEQ * HD;
#pragma unroll
    for (int rt = 0; rt < 2; ++rt)
#pragma unroll
        for (int kc = 0; kc < 2; ++kc) {
            size_t off = qkbase + (size_t)(qb0 + w * 32 + rt * 16 + lc) * HD + kc * 32 + lg * 8;
            qfh[rt][kc] = *(const bf16x8*)(qh + off);
            qfl[rt][kc] = *(const bf16x8*)(ql + off);
        }

    f32x4 ot[2][4];
#pragma unroll
    for (int i = 0; i < 2; ++i)
#pragma unroll
        for (int j = 0; j < 4; ++j) ot[i][j] = (f32x4)0.f;
    float m_[2] = {-3e38f, -3e38f};
    float s_[2] = {0.f, 0.f};

    const size_t vbase = (size_t)hn * HD * SEQ;

    for (int kt = 0; kt < SEQ; kt += 64) {
        __syncthreads();
#pragma unroll
        for (int i = 0; i < 2; ++i) {
            int f = tid + 256 * i, row = f >> 3, kb = (f & 7) * 8;
            size_t ksrc = qkbase + (size_t)(kt + row) * HD + kb;
            *(bf16x8*)&Ks[row][kb] = *(const bf16x8*)(kh + ksrc);
            size_t vsrc = vbase + (size_t)row * SEQ + kt + kb;   // row = d
            *(bf16x8*)&Vs[row][kb] = *(const bf16x8*)(vth + vsrc);
        }
        __syncthreads();

        f32x4 st[2][4];
#pragma unroll
        for (int i = 0; i < 2; ++i)
#pragma unroll
            for (int j = 0; j < 4; ++j) st[i][j] = (f32x4)0.f;
        __builtin_amdgcn_s_setprio(1);
#pragma unroll
        for (int jt = 0; jt < 4; ++jt)
#pragma unroll
            for (int kc = 0; kc < 2; ++kc) {
                bf16x8 k8 = *(const bf16x8*)&Ks[jt * 16 + lc][kc * 32 + lg * 8];
#pragma unroll
                for (int rt = 0; rt < 2; ++rt) {
                    st[rt][jt] = MFMA(k8, qfh[rt][kc], st[rt][jt], 0, 0, 0);
                    st[rt][jt] = MFMA(k8, qfl[rt][kc], st[rt][jt], 0, 0, 0);
                }
            }
        __builtin_amdgcn_s_setprio(0);

#pragma unroll
        for (int rt = 0; rt < 2; ++rt) {
            float t0 = fmaxf(fmaxf(st[rt][0][0], st[rt][0][1]),
                             fmaxf(st[rt][0][2], st[rt][0][3]));
            float t1 = fmaxf(fmaxf(st[rt][1][0], st[rt][1][1]),
                             fmaxf(st[rt][1][2], st[rt][1][3]));
            float t2 = fmaxf(fmaxf(st[rt][2][0], st[rt][2][1]),
                             fmaxf(st[rt][2][2], st[rt][2][3]));
            float t3 = fmaxf(fmaxf(st[rt][3][0], st[rt][3][1]),
                             fmaxf(st[rt][3][2], st[rt][3][3]));
            float t = fmaxf(fmaxf(t0, t1), fmaxf(t2, t3));
            t = fmaxf(t, __shfl_xor(t, 16));
            t = fmaxf(t, __shfl_xor(t, 32));
            if (__any(t - m_[rt] > 8.0f)) {
                float mnew = fmaxf(m_[rt], t);
                float resc = exp2_fast(m_[rt] - mnew);
                m_[rt] = mnew;
                s_[rt] *= resc;
#pragma unroll
                for (int dt = 0; dt < 4; ++dt) {
                    ot[rt][dt][0] *= resc; ot[rt][dt][1] *= resc;
                    ot[rt][dt][2] *= resc; ot[rt][dt][3] *= resc;
                }
            }
            const float mm = m_[rt];
#pragma unroll
            for (int jt = 0; jt < 4; ++jt) {
                float p0 = exp2_fast(st[rt][jt][0] - mm);
                float p1 = exp2_fast(st[rt][jt][1] - mm);
                float p2 = exp2_fast(st[rt][jt][2] - mm);
                float p3 = exp2_fast(st[rt][jt][3] - mm);
                s_[rt] += (p0 + p1) + (p2 + p3);
                u32x2 pk = {cvt_pk_bf16(p0, p1), cvt_pk_bf16(p2, p3)};
                *(u32x2*)&Pb[w][rt * 16 + lc][jt * 16 + lg * 4] = pk;
            }
        }

        bf16x8 pb[2][2];
#pragma unroll
        for (int rt = 0; rt < 2; ++rt)
#pragma unroll
            for (int jc = 0; jc < 2; ++jc)
                pb[rt][jc] = *(const bf16x8*)&Pb[w][rt * 16 + lc][jc * 32 + lg * 8];
        __builtin_amdgcn_s_setprio(1);
#pragma unroll
        for (int dt = 0; dt < 4; ++dt)
#pragma unroll
            for (int jc = 0; jc < 2; ++jc) {
                bf16x8 v8 = *(const bf16x8*)&Vs[dt * 16 + lc][jc * 32 + lg * 8];
#pragma unroll
                for (int rt = 0; rt < 2; ++rt)
                    ot[rt][dt] = MFMA(v8, pb[rt][jc], ot[rt][dt], 0, 0, 0);
            }
        __builtin_amdgcn_s_setprio(0);
    }

    const int h = hn >> 1, n = hn & 1;
#pragma unroll
    for (int rt = 0; rt < 2; ++rt) {
        float v = s_[rt];
        v += __shfl_xor(v, 16);
        v += __shfl_xor(v, 32);
        s_[rt] = 1.f / v;
    }
#pragma unroll
    for (int rt = 0; rt < 2; ++rt) {
        const int srow = qb0 + w * 32 + rt * 16 + lc;
        size_t rowoff = (size_t)(n * SEQ + srow) * DM + h * HD;
#pragma unroll
        for (int dt = 0; dt < 4; ++dt) {
            u16x4 hv, lv;
#pragma unroll
            for (int r = 0; r < 4; ++r) {
                float y = ot[rt][dt][r] * s_[rt];
                u16 hh, ll; split2(y, hh, ll);
                hv[r] = hh; lv[r] = ll;
            }
            size_t idx = rowoff + dt * 16 + lg * 4;
            *(u16x4*)(yh + idx) = hv;
            *(u16x4*)(yl + idx) = lv;
        }
    }
}

// ---------------------------------------------------------------------------
extern "C" void kernel_launch(void* const* d_in, const int* in_sizes, int n_in,
                              void* d_out, int out_size, void* d_ws, size_t ws_size,
                              hipStream_t stream)
{
    const float* query = (const float*)d_in[0];
    const float* key_  = (const float*)d_in[1];
    const float* value = (const float*)d_in[2];
    const float* Wq = (const float*)d_in[3];
    const float* bq = (const float*)d_in[4];
    const float* Wk = (const float*)d_in[5];
    const float* bk = (const float*)d_in[6];
    const float* Wv = (const float*)d_in[7];
    const float* bv = (const float*)d_in[8];
    const float* Wo = (const float*)d_in[9];
    const float* bo = (const float*)d_in[10];
    float* out = (float*)d_out;

    // ws map (112 MiB, offsets unchanged from proven rounds):
    //   0MB  wh[4]   (8MB)     8MB  wl[4]   (8MB, only Wo-lo slot used)
    //  16MB  qh ql kh (kl unused) vth (vtl unused)
    //  64MB  xh[3]  (24MB)  -- reused after QKV: yh @64MB, yl @72MB
    char* p = (char*)d_ws;
    u16* wh  = (u16*)(p);
    u16* wl  = (u16*)(p + 8388608ull);
    u16* qh  = (u16*)(p + 16777216ull);
    u16* ql  = (u16*)(p + 25165824ull);
    u16* kh  = (u16*)(p + 33554432ull);
    u16* vth = (u16*)(p + 50331648ull);
    u16* xh  = (u16*)(p + 67108864ull);
    u16* yh  = (u16*)(p + 67108864ull);
    u16* yl  = (u16*)(p + 75497472ull);

    presplit<<<dim3(256, 7), 256, 0, stream>>>(
        query, key_, value, Wq, Wk, Wv, Wo, xh, wh, wl);

    gemm_qkv<<<dim3(8, 32, 3), 256, 0, stream>>>(
        xh, wh, bq, bk, bv, qh, ql, kh, vth);

    attn_k<<<dim3(16, 32), 256, 0, stream>>>(qh, ql, kh, vth, yh, yl);

    gemm_proj<<<dim3(8, 32), 256, 0, stream>>>(
        yh, yl, wh + 3145728ull, wl + 3145728ull, bo, out);
}